// Round 8
// baseline (7280.030 us; speedup 1.0000x reference)
//
#include <hip/hip_runtime.h>
#include <hip/hip_bf16.h>
#include <math.h>

#define NB 64
#define NT 512
#define NDIN 256
#define NH 1024
#define NG 4096
#define NDOUT 256

// 256 blocks. Per block: waves 0-3 = z (one 16-row tile each, full K, no splitK);
// wave 4 = proj task (mbp x nbp x kq); wave 5 (blocks 0-63) = outred.
#define GRIDN 256
#define LDSB 81920         // 80K Wz only -- no reduce slabs at all
#define HSTEP 131072       // shorts per h time-slab: [v(2)][ku(32)][mb(4)][512]

typedef __attribute__((ext_vector_type(8))) short short8;
typedef __attribute__((ext_vector_type(4))) float float4v;

__device__ __forceinline__ float sigf(float v) { return 1.0f / (1.0f + expf(-v)); }

__device__ __forceinline__ unsigned short bf_hi(float v, float* back) {
    __hip_bfloat16 b = __float2bfloat16(v);
    *back = __bfloat162float(b);
    union { __hip_bfloat16 b; unsigned short u; } cv; cv.b = b;
    return cv.u;
}

// ---- device-coherent (LLC) helpers ----
#define LD4(o0,o1,o2,o3,p0,p1,p2,p3)                                             \
  asm volatile("global_load_dwordx4 %0, %4, off sc0 sc1\n\t"                     \
               "global_load_dwordx4 %1, %5, off sc0 sc1\n\t"                     \
               "global_load_dwordx4 %2, %6, off sc0 sc1\n\t"                     \
               "global_load_dwordx4 %3, %7, off sc0 sc1\n\t"                     \
               "s_waitcnt vmcnt(0)"                                              \
               : "=&v"(o0),"=&v"(o1),"=&v"(o2),"=&v"(o3)                         \
               : "v"(p0),"v"(p1),"v"(p2),"v"(p3) : "memory")

__device__ __forceinline__ void sc_store_short(unsigned short* p, unsigned short v) {
    asm volatile("global_store_short %0, %1, off sc0 sc1" :: "v"(p), "v"((unsigned)v) : "memory");
}
__device__ __forceinline__ void sc_store_dword(float* p, float v) {
    asm volatile("global_store_dword %0, %1, off sc0 sc1" :: "v"(p), "v"(v) : "memory");
}

// Two-level tree barrier (validated r6/r7). Monotonic counters, no reset race.
__device__ __forceinline__ void gbar_tree(unsigned* bar, int bid, int t) {
    asm volatile("s_waitcnt vmcnt(0)" ::: "memory");   // drain own sc-stores
    __syncthreads();
    if (threadIdx.x == 0) {
        unsigned* gcnt = bar + ((unsigned)bid >> 3) * 32;   // 32 groups of 8
        unsigned* root = bar + 32 * 32;
        unsigned old = __hip_atomic_fetch_add(gcnt, 1u, __ATOMIC_RELAXED, __HIP_MEMORY_SCOPE_AGENT);
        if (old == (unsigned)t * 8u + 7u)                   // last of my group this epoch
            __hip_atomic_fetch_add(root, 1u, __ATOMIC_RELAXED, __HIP_MEMORY_SCOPE_AGENT);
        const unsigned tgt = (unsigned)(t + 1) * 32u;
        while (__hip_atomic_load(root, __ATOMIC_RELAXED, __HIP_MEMORY_SCOPE_AGENT) < tgt) {}
    }
    __syncthreads();
}

__global__ void zero_kernel(float* __restrict__ p, int n) {
    int i = blockIdx.x * 256 + threadIdx.x;
    if (i < n) p[i] = 0.0f;
}

// W (= [Wx;Wh], 1280 x 4096) -> per-block LDS image:
// [jb(256)][ku(40)][plane(2)][lane(64)][j(8)]  (80 KB per jb, contiguous)
__global__ void packWz_kernel(const float* __restrict__ Wx, const float* __restrict__ Wh,
                              unsigned short* __restrict__ Wzf) {
    int e = blockIdx.x * 256 + threadIdx.x;
    if (e >= 1280 * 4096) return;
    int k = e >> 12, col = e & 4095;
    float w = (k < NDIN) ? Wx[(size_t)k * NG + col] : Wh[(size_t)(k - NDIN) * NG + col];
    float back;
    unsigned short w0 = bf_hi(w, &back);
    unsigned short w1 = bf_hi(w - back, &back);
    int g = col >> 10, j = col & 1023;
    int jb = j >> 2, jc = j & 3, n = g * 4 + jc;
    int ku = k >> 5, kr = k & 31;
    int lane = (kr >> 3) * 16 + n, j8 = kr & 7;
    size_t off = ((size_t)jb * 40 + ku) * 1024 + lane * 8 + j8;
    Wzf[off] = w0;          // plane 0 (hi)
    Wzf[off + 512] = w1;    // plane 1 (lo)
}

// x ([64][512][256]) -> A-frag order [t][ku(8)][mb(4)][lane(64)][j(8)], hi/lo
__global__ void packX_kernel(const float* __restrict__ x,
                             unsigned short* __restrict__ xf0, unsigned short* __restrict__ xf1) {
    int e = blockIdx.x * 256 + threadIdx.x;
    if (e >= NB * NT * NDIN) return;
    int k = e & 255, t = (e >> 8) & 511, m = e >> 17;
    float v = x[e];
    float back;
    unsigned short a0 = bf_hi(v, &back);
    unsigned short a1 = bf_hi(v - back, &back);
    int ku = k >> 5, kr = k & 31, mb = m >> 4;
    int lane = (kr >> 3) * 16 + (m & 15), j = kr & 7;
    size_t off = ((((size_t)t * 8 + ku) * 4 + mb) * 64 + lane) * 8 + j;
    xf0[off] = a0; xf1[off] = a1;
}

// Wo (1024 x 256) -> B-frag order [nb(16)][ku(32)][lane(64)][j(8)], hi/lo
__global__ void packWo_kernel(const float* __restrict__ Wo,
                              unsigned short* __restrict__ Wo0f, unsigned short* __restrict__ Wo1f) {
    int e = blockIdx.x * 256 + threadIdx.x;
    if (e >= NH * NDOUT) return;
    int k = e >> 8, n = e & 255;
    float w = Wo[e];
    float back;
    unsigned short w0 = bf_hi(w, &back);
    unsigned short w1 = bf_hi(w - back, &back);
    int nb = n >> 4, nl = n & 15, ku = k >> 5, kr = k & 31;
    int lane = (kr >> 3) * 16 + nl, j = kr & 7;
    size_t off = (((size_t)nb * 32 + ku) * 64 + lane) * 8 + j;
    Wo0f[off] = w0; Wo1f[off] = w1;
}

// x-partial for step tt into the 4 acc quads (wave's mb tile, 8 x-ku, 24 MFMA)
#define XPART(tt) do {                                                            \
    _Pragma("unroll")                                                             \
    for (int xku = 0; xku < 8; ++xku) {                                           \
        const unsigned short* _p0 = xf0 + ((size_t)(tt) * 8 + xku) * 2048 + mb * 512 + lane8; \
        const unsigned short* _p1 = xf1 + ((size_t)(tt) * 8 + xku) * 2048 + mb * 512 + lane8; \
        short8 _X0 = *(const short8*)_p0;                                         \
        short8 _X1 = *(const short8*)_p1;                                         \
        const unsigned short* _wp = wlds + xku * 1024 + lane8;                    \
        short8 _Wh = *(const short8*)_wp;                                         \
        short8 _Wl = *(const short8*)(_wp + 512);                                 \
        float4v a = qacc[xku & 3];                                                \
        a = __builtin_amdgcn_mfma_f32_16x16x32_bf16(_X0, _Wh, a, 0, 0, 0);        \
        a = __builtin_amdgcn_mfma_f32_16x16x32_bf16(_X0, _Wl, a, 0, 0, 0);        \
        a = __builtin_amdgcn_mfma_f32_16x16x32_bf16(_X1, _Wh, a, 0, 0, 0);        \
        qacc[xku & 3] = a;                                                        \
    }                                                                             \
} while (0)

// ================= 256-block persistent kernel: no-splitK z =================
__global__ __launch_bounds__(512, 2) void persist_z256_kernel(
    const unsigned short* __restrict__ Wzf,
    const unsigned short* __restrict__ xf0, const unsigned short* __restrict__ xf1,
    const unsigned short* __restrict__ Wo0f, const unsigned short* __restrict__ Wo1f,
    unsigned short* __restrict__ hh, float* __restrict__ opart,
    const float* __restrict__ bias, const float* __restrict__ bo,
    float* __restrict__ out, unsigned* __restrict__ bar)
{
    extern __shared__ char dynlds[];
    unsigned short* wlds = (unsigned short*)dynlds;          // [40][2][64][8] = 80 KB

    const int bid = blockIdx.x, tid = threadIdx.x;
    const int lane = tid & 63, w = tid >> 6;
    const int lane8 = lane * 8;

    // ---- one-time: W slice -> LDS (80 KB straight copy) ----
    {
        const unsigned short* src = Wzf + (size_t)bid * 40960;
        for (int i = tid; i < 5120; i += 512)
            *(short8*)(wlds + i * 8) = *(const short8*)(src + i * 8);
    }
    __syncthreads();

    // ================= role constants =================
    // z waves (0-3): wave owns mb = w (16 batch rows), all 16 z-cols, full K.
    const int mb = w & 3;
    // gate owner-lane constants (col = lane&15 < 4)
    const int jc = lane & 3;
    const int gj = bid * 4 + jc;
    const float b_i = bias[gj], b_f = bias[NH + gj];
    const float b_g = bias[2 * NH + gj], b_o = bias[3 * NH + gj];
    const int gbase = (lane & 48) | jc;                      // shfl gather base
    const int kuh = gj >> 5, krh = gj & 31;
    const size_t hbo = ((size_t)(kuh * 4 + mb)) * 512
                     + ((krh >> 3) * 16 + (lane >> 4) * 4) * 8 + (krh & 7);
    float creg[4] = {0.f, 0.f, 0.f, 0.f};                    // cell state (owner lanes)

    // proj constants (wave 4): task bid = (mbp, nbp, kq)
    const int kq = bid & 3, nbp = (bid >> 2) & 15, mbp = bid >> 6;

    float4v qacc[4];
    #pragma unroll
    for (int q = 0; q < 4; ++q) qacc[q] = (float4v){0.f, 0.f, 0.f, 0.f};
    if (w < 4) XPART(0);                                     // prologue: x(0) partial

    for (int t = 0; t <= NT + 1; ++t) {
        const unsigned short* hb0 = hh + (size_t)t * HSTEP;  // h(t) slab (hi plane)

        if (w < 4) {
            if (t < NT) {
                // ---- z h-part: 32 ku x 3 MFMA, 4-ku load groups, quads by ku&3 ----
                for (int kg = 0; kg < 8; ++kg) {
                    short8 Ah[4], Al[4], Bh[4], Bl[4];
                    #pragma unroll
                    for (int u = 0; u < 4; ++u) {
                        const int ku = kg * 4 + u;
                        const unsigned short* p = hb0 + (size_t)ku * 2048 + mb * 512 + lane8;
                        Ah[u] = *(const short8*)p;
                        Al[u] = *(const short8*)(p + 65536);
                        const unsigned short* wp = wlds + (8 + ku) * 1024 + lane8;
                        Bh[u] = *(const short8*)wp;
                        Bl[u] = *(const short8*)(wp + 512);
                    }
                    #pragma unroll
                    for (int u = 0; u < 4; ++u) {
                        float4v a = qacc[u];
                        a = __builtin_amdgcn_mfma_f32_16x16x32_bf16(Ah[u], Bh[u], a, 0, 0, 0);
                        a = __builtin_amdgcn_mfma_f32_16x16x32_bf16(Ah[u], Bl[u], a, 0, 0, 0);
                        a = __builtin_amdgcn_mfma_f32_16x16x32_bf16(Al[u], Bh[u], a, 0, 0, 0);
                        qacc[u] = a;
                    }
                }
                // final z for this wave's tile (16 rows x 16 cols), in-register
                float4v z4 = qacc[0] + qacc[1] + qacc[2] + qacc[3];

                // reset quads with x(t+1) partial (loads overlap the shfl/gate phase)
                #pragma unroll
                for (int q = 0; q < 4; ++q) qacc[q] = (float4v){0.f, 0.f, 0.f, 0.f};
                if (t + 1 < NT) XPART(t + 1);

                // cross-lane gate gather: cols jc, 4+jc, 8+jc, 12+jc -> owner lanes
                float zi[4], zf[4], zg[4], zo[4];
                #pragma unroll
                for (int r = 0; r < 4; ++r) {
                    zi[r] = __shfl(z4[r], gbase, 64);
                    zf[r] = __shfl(z4[r], gbase + 4, 64);
                    zg[r] = __shfl(z4[r], gbase + 8, 64);
                    zo[r] = __shfl(z4[r], gbase + 12, 64);
                }
                if ((lane & 12) == 0) {                      // 16 owner lanes/wave
                    unsigned short* hw = hh + (size_t)(t + 1) * HSTEP;
                    #pragma unroll
                    for (int r = 0; r < 4; ++r) {
                        float iv = sigf(zi[r] + b_i), fv = sigf(zf[r] + b_f);
                        float gv = tanhf(zg[r] + b_g), ov = sigf(zo[r] + b_o);
                        creg[r] = fv * creg[r] + iv * gv;
                        float hv = ov * tanhf(creg[r]);
                        float back;
                        unsigned short h0 = bf_hi(hv, &back);
                        unsigned short h1 = bf_hi(hv - back, &back);
                        sc_store_short(hw + hbo + r * 8, h0);
                        sc_store_short(hw + hbo + r * 8 + 65536, h1);   // lo plane
                    }
                }
            }
        } else if (w == 4) {
            // ---- proj: tile (mbp,nbp) x K-quarter kq of h(t-1)@Wo, in-wave ----
            if (t >= 1 && t <= NT) {
                float4v pa = (float4v){0.f, 0.f, 0.f, 0.f};
                float4v pb = (float4v){0.f, 0.f, 0.f, 0.f};
                #pragma unroll
                for (int i = 0; i < 8; ++i) {
                    const int kup = kq * 8 + i;
                    const unsigned short* ap = hb0 + (size_t)(kup * 4 + mbp) * 512 + lane8;
                    short8 Ahi = *(const short8*)ap;
                    short8 Alo = *(const short8*)(ap + 65536);
                    const size_t wo = (((size_t)nbp * 32 + kup) * 64) * 8 + lane8;
                    short8 Whi = *(const short8*)(Wo0f + wo);
                    short8 Wlo = *(const short8*)(Wo1f + wo);
                    float4v& pc = (i & 1) ? pb : pa;
                    pc = __builtin_amdgcn_mfma_f32_16x16x32_bf16(Ahi, Whi, pc, 0, 0, 0);
                    pc = __builtin_amdgcn_mfma_f32_16x16x32_bf16(Ahi, Wlo, pc, 0, 0, 0);
                    pc = __builtin_amdgcn_mfma_f32_16x16x32_bf16(Alo, Whi, pc, 0, 0, 0);
                }
                float4v pacc = pa + pb;
                const int pcol = nbp * 16 + (lane & 15);
                float* op = opart + (size_t)(t & 1) * 65536 + (size_t)kq * 16384;
                #pragma unroll
                for (int r = 0; r < 4; ++r) {
                    const int prow = mbp * 16 + (lane >> 4) * 4 + r;
                    sc_store_dword(op + (size_t)prow * NDOUT + pcol, pacc[r]);
                }
            }
        } else if (w == 5 && bid < NB) {
            // ---- outred: batch row m=bid, cols lane*4..+3, 4 K-quarters ----
            if (t >= 2) {
                const float* op = opart + (size_t)((t - 1) & 1) * 65536;
                const int oc4 = lane * 4;
                float4v s0, s1, s2, s3;
                LD4(s0, s1, s2, s3,
                    &op[(size_t)bid * NDOUT + oc4],
                    &op[16384 + (size_t)bid * NDOUT + oc4],
                    &op[32768 + (size_t)bid * NDOUT + oc4],
                    &op[49152 + (size_t)bid * NDOUT + oc4]);
                float4v bv = *(const float4v*)&bo[oc4];
                float4v v = s0 + s1 + s2 + s3 + bv;
                float4v rr;
                rr[0] = fmaxf(v[0], 0.f); rr[1] = fmaxf(v[1], 0.f);
                rr[2] = fmaxf(v[2], 0.f); rr[3] = fmaxf(v[3], 0.f);
                *(float4v*)&out[((size_t)bid * NT + (t - 2)) * NDOUT + oc4] = rr;
            }
        }

        gbar_tree(bar, bid, t);
    }
}

extern "C" void kernel_launch(void* const* d_in, const int* in_sizes, int n_in,
                              void* d_out, int out_size, void* d_ws, size_t ws_size,
                              hipStream_t stream) {
    const float* x  = (const float*)d_in[0];
    const float* Wx = (const float*)d_in[1];
    const float* Wh = (const float*)d_in[2];
    const float* b  = (const float*)d_in[3];
    const float* Wo = (const float*)d_in[4];
    const float* bo = (const float*)d_in[5];
    float* out = (float*)d_out;
    char* ws = (char*)d_ws;

    const size_t hh_bytes = (size_t)(NT + 1) * HSTEP * 2;    // 513 x 256 KB

    size_t off = 0;
    unsigned* bar = (unsigned*)(ws + off);             off += 8192;   // tree barrier lines
    unsigned short* hh = (unsigned short*)(ws + off);  off += hh_bytes;
    size_t zero_floats = (8192 + (size_t)HSTEP * 2) / 4;      // bar + hh slab0
    float* opart = (float*)(ws + off);                 off += (size_t)2 * 4 * NB * NDOUT * 4;  // 512 KB
    unsigned short* Wzf = (unsigned short*)(ws + off); off += (size_t)1280 * 4096 * 2 * 2;     // 21 MB
    unsigned short* Wo0f = (unsigned short*)(ws + off); off += (size_t)NH * NDOUT * 2;
    unsigned short* Wo1f = (unsigned short*)(ws + off); off += (size_t)NH * NDOUT * 2;
    unsigned short* xf0 = (unsigned short*)(ws + off); off += (size_t)NB * NT * NDIN * 2;
    unsigned short* xf1 = (unsigned short*)(ws + off); off += (size_t)NB * NT * NDIN * 2;

    zero_kernel<<<(int)((zero_floats + 255) / 256), 256, 0, stream>>>((float*)ws, (int)zero_floats);
    packWz_kernel<<<(1280 * 4096 + 255) / 256, 256, 0, stream>>>(Wx, Wh, Wzf);
    packX_kernel<<<(NB * NT * NDIN + 255) / 256, 256, 0, stream>>>(x, xf0, xf1);
    packWo_kernel<<<(NH * NDOUT + 255) / 256, 256, 0, stream>>>(Wo, Wo0f, Wo1f);

    void* args[] = {(void*)&Wzf, (void*)&xf0, (void*)&xf1, (void*)&Wo0f, (void*)&Wo1f,
                    (void*)&hh, (void*)&opart, (void*)&b, (void*)&bo, (void*)&out, (void*)&bar};
    hipLaunchCooperativeKernel((void*)persist_z256_kernel, dim3(GRIDN), dim3(512),
                               args, (unsigned)LDSB, stream);
}

// Round 9
// 4567.422 us; speedup vs baseline: 1.5939x; 1.5939x over previous
//
#include <hip/hip_runtime.h>
#include <hip/hip_bf16.h>
#include <math.h>

#define NB 64
#define NT 512
#define NDIN 256
#define NH 1024
#define NG 4096
#define NDOUT 256

// 256 blocks: ALL do z (4 h-cols each, 8-wave splitK) AND proj (1 tile x K-quarter);
// blocks [0,8) also outred.
#define GRIDN 256
#define LDSB 122880        // 80K Wz + 32K red(z) + 8K red2(proj)
#define HSTEP 131072       // shorts per h time-slab: [v(2)][ku(32)][mb(4)][512]

typedef __attribute__((ext_vector_type(8))) short short8;
typedef __attribute__((ext_vector_type(4))) float float4v;
typedef __attribute__((ext_vector_type(2))) unsigned uint2v;

__device__ __forceinline__ float sigf(float v) { return 1.0f / (1.0f + expf(-v)); }

__device__ __forceinline__ unsigned short bf_hi(float v, float* back) {
    __hip_bfloat16 b = __float2bfloat16(v);
    *back = __bfloat162float(b);
    union { __hip_bfloat16 b; unsigned short u; } cv; cv.b = b;
    return cv.u;
}

// ---- device-coherent (LLC) helpers ----
#define LD4(o0,o1,o2,o3,p0,p1,p2,p3)                                             \
  asm volatile("global_load_dwordx4 %0, %4, off sc0 sc1\n\t"                     \
               "global_load_dwordx4 %1, %5, off sc0 sc1\n\t"                     \
               "global_load_dwordx4 %2, %6, off sc0 sc1\n\t"                     \
               "global_load_dwordx4 %3, %7, off sc0 sc1\n\t"                     \
               "s_waitcnt vmcnt(0)"                                              \
               : "=&v"(o0),"=&v"(o1),"=&v"(o2),"=&v"(o3)                         \
               : "v"(p0),"v"(p1),"v"(p2),"v"(p3) : "memory")

__device__ __forceinline__ void sc_store_dword(float* p, float v) {
    asm volatile("global_store_dword %0, %1, off sc0 sc1" :: "v"(p), "v"(v) : "memory");
}
__device__ __forceinline__ void sc_store_dwordx2(unsigned short* p, uint2v v) {
    asm volatile("global_store_dwordx2 %0, %1, off sc0 sc1" :: "v"(p), "v"(v) : "memory");
}

// ---- flag-based grid barrier (no atomic contention) ----
// Arrival: each block stores epoch t+1 to its own 128B line (after vmcnt drain).
// Gather: block 0's threads 0..255 each poll one flag line (parallel loads),
// then thread 0 publishes the epoch. Everyone polls the publish word.
// Monotonic epochs -> no reset race. Serial depth ~3 LLC hops.
__device__ __forceinline__ void gbar_arrive(unsigned* bar, int bid, int t) {
    asm volatile("s_waitcnt vmcnt(0)" ::: "memory");   // drain own sc-stores
    __syncthreads();
    if (threadIdx.x == 0)
        __hip_atomic_store(bar + (unsigned)bid * 32, (unsigned)(t + 1),
                           __ATOMIC_RELAXED, __HIP_MEMORY_SCOPE_AGENT);
}

__device__ __forceinline__ void gbar_wait(unsigned* bar, int bid, int t) {
    unsigned* pub = bar + 256 * 32;
    if (bid == 0) {
        if (threadIdx.x < 256) {
            unsigned* f = bar + (unsigned)threadIdx.x * 32;
            while (__hip_atomic_load(f, __ATOMIC_RELAXED, __HIP_MEMORY_SCOPE_AGENT)
                   < (unsigned)(t + 1)) {}
        }
        __syncthreads();
        if (threadIdx.x == 0)
            __hip_atomic_store(pub, (unsigned)(t + 1),
                               __ATOMIC_RELAXED, __HIP_MEMORY_SCOPE_AGENT);
    }
    if (threadIdx.x == 0) {
        while (__hip_atomic_load(pub, __ATOMIC_RELAXED, __HIP_MEMORY_SCOPE_AGENT)
               < (unsigned)(t + 1)) {}
    }
    __syncthreads();
}

__global__ void zero_kernel(float* __restrict__ p, int n) {
    int i = blockIdx.x * 256 + threadIdx.x;
    if (i < n) p[i] = 0.0f;
}

// W (= [Wx;Wh], 1280 x 4096) -> per-block LDS image:
// [jb(256)][ku(40)][plane(2)][lane(64)][j(8)]  (80 KB per jb, contiguous)
__global__ void packWz_kernel(const float* __restrict__ Wx, const float* __restrict__ Wh,
                              unsigned short* __restrict__ Wzf) {
    int e = blockIdx.x * 256 + threadIdx.x;
    if (e >= 1280 * 4096) return;
    int k = e >> 12, col = e & 4095;
    float w = (k < NDIN) ? Wx[(size_t)k * NG + col] : Wh[(size_t)(k - NDIN) * NG + col];
    float back;
    unsigned short w0 = bf_hi(w, &back);
    unsigned short w1 = bf_hi(w - back, &back);
    int g = col >> 10, j = col & 1023;
    int jb = j >> 2, jc = j & 3, n = g * 4 + jc;
    int ku = k >> 5, kr = k & 31;
    int lane = (kr >> 3) * 16 + n, j8 = kr & 7;
    size_t off = ((size_t)jb * 40 + ku) * 1024 + lane * 8 + j8;
    Wzf[off] = w0;          // plane 0 (hi)
    Wzf[off + 512] = w1;    // plane 1 (lo)
}

// x ([64][512][256]) -> A-frag order [t][ku(8)][mb(4)][lane(64)][j(8)], hi/lo
__global__ void packX_kernel(const float* __restrict__ x,
                             unsigned short* __restrict__ xf0, unsigned short* __restrict__ xf1) {
    int e = blockIdx.x * 256 + threadIdx.x;
    if (e >= NB * NT * NDIN) return;
    int k = e & 255, t = (e >> 8) & 511, m = e >> 17;
    float v = x[e];
    float back;
    unsigned short a0 = bf_hi(v, &back);
    unsigned short a1 = bf_hi(v - back, &back);
    int ku = k >> 5, kr = k & 31, mb = m >> 4;
    int lane = (kr >> 3) * 16 + (m & 15), j = kr & 7;
    size_t off = ((((size_t)t * 8 + ku) * 4 + mb) * 64 + lane) * 8 + j;
    xf0[off] = a0; xf1[off] = a1;
}

// Wo (1024 x 256) -> B-frag order [nb(16)][ku(32)][lane(64)][j(8)], hi/lo
__global__ void packWo_kernel(const float* __restrict__ Wo,
                              unsigned short* __restrict__ Wo0f, unsigned short* __restrict__ Wo1f) {
    int e = blockIdx.x * 256 + threadIdx.x;
    if (e >= NH * NDOUT) return;
    int k = e >> 8, n = e & 255;
    float w = Wo[e];
    float back;
    unsigned short w0 = bf_hi(w, &back);
    unsigned short w1 = bf_hi(w - back, &back);
    int nb = n >> 4, nl = n & 15, ku = k >> 5, kr = k & 31;
    int lane = (kr >> 3) * 16 + nl, j = kr & 7;
    size_t off = (((size_t)nb * 32 + ku) * 64 + lane) * 8 + j;
    Wo0f[off] = w0; Wo1f[off] = w1;
}

// z h-load set (one ku = w*4+kk of the h slab): 8 x 16B loads
#define ZLOAD(S0, S1, kk) do {                                                    \
    const unsigned short* _p = hb0 + (size_t)(w4 + (kk)) * 2048 + lane8;          \
    S0[0] = *(const short8*)(_p);        S0[1] = *(const short8*)(_p + 512);      \
    S0[2] = *(const short8*)(_p + 1024); S0[3] = *(const short8*)(_p + 1536);     \
    const unsigned short* _q = _p + 65536;                                        \
    S1[0] = *(const short8*)(_q);        S1[1] = *(const short8*)(_q + 512);      \
    S1[2] = *(const short8*)(_q + 1024); S1[3] = *(const short8*)(_q + 1536);     \
} while (0)

// z MFMA set for one h-ku (3 planes x 4 mb)
#define ZMFMA(S0, S1, kk) do {                                                    \
    const unsigned short* _wp = wlds + (8 + w4 + (kk)) * 1024 + lane8;            \
    short8 _Wh = *(const short8*)(_wp);                                           \
    short8 _Wl = *(const short8*)(_wp + 512);                                     \
    acc[0] = __builtin_amdgcn_mfma_f32_16x16x32_bf16(S0[0], _Wh, acc[0], 0, 0, 0);\
    acc[0] = __builtin_amdgcn_mfma_f32_16x16x32_bf16(S0[0], _Wl, acc[0], 0, 0, 0);\
    acc[0] = __builtin_amdgcn_mfma_f32_16x16x32_bf16(S1[0], _Wh, acc[0], 0, 0, 0);\
    acc[1] = __builtin_amdgcn_mfma_f32_16x16x32_bf16(S0[1], _Wh, acc[1], 0, 0, 0);\
    acc[1] = __builtin_amdgcn_mfma_f32_16x16x32_bf16(S0[1], _Wl, acc[1], 0, 0, 0);\
    acc[1] = __builtin_amdgcn_mfma_f32_16x16x32_bf16(S1[1], _Wh, acc[1], 0, 0, 0);\
    acc[2] = __builtin_amdgcn_mfma_f32_16x16x32_bf16(S0[2], _Wh, acc[2], 0, 0, 0);\
    acc[2] = __builtin_amdgcn_mfma_f32_16x16x32_bf16(S0[2], _Wl, acc[2], 0, 0, 0);\
    acc[2] = __builtin_amdgcn_mfma_f32_16x16x32_bf16(S1[2], _Wh, acc[2], 0, 0, 0);\
    acc[3] = __builtin_amdgcn_mfma_f32_16x16x32_bf16(S0[3], _Wh, acc[3], 0, 0, 0);\
    acc[3] = __builtin_amdgcn_mfma_f32_16x16x32_bf16(S0[3], _Wl, acc[3], 0, 0, 0);\
    acc[3] = __builtin_amdgcn_mfma_f32_16x16x32_bf16(S1[3], _Wh, acc[3], 0, 0, 0);\
} while (0)

// x-partial for step tt: wave's x-ku = w, 4 mb x 3 MFMA, result REPLACES acc
#define XPART(tt) do {                                                            \
    const unsigned short* _xp0 = xf0 + ((size_t)(tt) * 8 + w) * 2048 + lane8;     \
    const unsigned short* _xp1 = xf1 + ((size_t)(tt) * 8 + w) * 2048 + lane8;     \
    short8 _X0[4], _X1[4];                                                        \
    _Pragma("unroll")                                                             \
    for (int _mb = 0; _mb < 4; ++_mb) {                                           \
        _X0[_mb] = *(const short8*)(_xp0 + _mb * 512);                            \
        _X1[_mb] = *(const short8*)(_xp1 + _mb * 512);                            \
    }                                                                             \
    const short8 _Wh = *(const short8*)(wlds + w * 1024 + lane8);                 \
    const short8 _Wl = *(const short8*)(wlds + w * 1024 + 512 + lane8);           \
    _Pragma("unroll")                                                             \
    for (int _mb = 0; _mb < 4; ++_mb) {                                           \
        float4v _a = (float4v){0.f, 0.f, 0.f, 0.f};                               \
        _a = __builtin_amdgcn_mfma_f32_16x16x32_bf16(_X0[_mb], _Wh, _a, 0, 0, 0); \
        _a = __builtin_amdgcn_mfma_f32_16x16x32_bf16(_X0[_mb], _Wl, _a, 0, 0, 0); \
        _a = __builtin_amdgcn_mfma_f32_16x16x32_bf16(_X1[_mb], _Wh, _a, 0, 0, 0); \
        acc[_mb] = _a;                                                            \
    }                                                                             \
} while (0)

// ================= 256-block persistent kernel (r7 base + flag barrier) ========
__global__ __launch_bounds__(512, 2) void persist_z256_kernel(
    const unsigned short* __restrict__ Wzf,
    const unsigned short* __restrict__ xf0, const unsigned short* __restrict__ xf1,
    const unsigned short* __restrict__ Wo0f, const unsigned short* __restrict__ Wo1f,
    unsigned short* __restrict__ hh, float* __restrict__ opart,
    const float* __restrict__ bias, const float* __restrict__ bo,
    float* __restrict__ out, unsigned* __restrict__ bar)
{
    extern __shared__ char dynlds[];
    unsigned short* wlds = (unsigned short*)dynlds;          // [40][2][64][8] = 80 KB
    float* red  = (float*)(dynlds + 81920);                  // [8][1024] z splitK slabs
    float* red2 = (float*)(dynlds + 114688);                 // [8][256] proj slabs

    const int bid = blockIdx.x, tid = threadIdx.x;
    const int lane = tid & 63, w = tid >> 6;
    const int lane8 = lane * 8, w4 = w * 4;

    // ---- one-time: W slice -> LDS (80 KB straight copy) ----
    {
        const unsigned short* src = Wzf + (size_t)bid * 40960;
        for (int i = tid; i < 5120; i += 512)
            *(short8*)(wlds + i * 8) = *(const short8*)(src + i * 8);
    }
    __syncthreads();

    // ---- per-thread gate-math constants (threads 0..255 own (row, col)) ----
    const int grow = tid >> 2, gjc = tid & 3;
    const int gj = bid * 4 + gjc;                            // global h-col
    const float b_i = bias[gj], b_f = bias[NH + gj], b_g = bias[2 * NH + gj], b_o = bias[3 * NH + gj];
    const int zb = ((grow >> 4) * 64 + (((grow & 15) >> 2) * 16) + gjc) * 4 + (grow & 3);
    // packed h-store address (4 cols of a row are 4 consecutive shorts)
    const int kuh = bid >> 3, krh3 = (bid & 7) >> 1, j80 = (bid & 1) * 4;
    const size_t hp = ((size_t)(kuh * 4 + (grow >> 4))) * 512
                    + (krh3 * 16 + (grow & 15)) * 8 + j80;
    float creg = 0.0f;                                       // cell state, register-resident

    // ---- proj constants: block owns tile (mbp,nbp) x K-quarter kq; wave owns 1 ku
    const int kq = bid & 3, tt0 = bid >> 2;
    const int mbp = tt0 >> 4, nbp = tt0 & 15;
    const int kup = kq * 8 + w;
    const size_t wo_off = (((size_t)nbp * 32 + kup) * 64 + lane) * 8;
    const short8 PWh = *(const short8*)(Wo0f + wo_off);      // Wo frags loop-invariant
    const short8 PWl = *(const short8*)(Wo1f + wo_off);

    float4v acc[4];
    XPART(0);                                                // prologue: x(0) partial

    for (int t = 0; t <= NT + 1; ++t) {
        const int projA = (t >= 1 && t <= NT);
        const unsigned short* hb0 = hh + (size_t)t * HSTEP;  // h(t) slab, hi plane

        // proj loads issued first (deepest latency hiding)
        short8 PAh, PAl;
        if (projA) {
            const unsigned short* ap = hb0 + (size_t)(kup * 4 + mbp) * 512 + lane8;
            PAh = *(const short8*)ap;
            PAl = *(const short8*)(ap + 65536);
        }

        if (t < NT) {
            // ---- z h-part: K=1024 over 4 ku/wave, a/b double-buffered loads ----
            short8 A0a[4], A1a[4], A0b[4], A1b[4];
            ZLOAD(A0a, A1a, 0);
            ZLOAD(A0b, A1b, 1);
            ZMFMA(A0a, A1a, 0);
            ZLOAD(A0a, A1a, 2);
            ZMFMA(A0b, A1b, 1);
            ZLOAD(A0b, A1b, 3);
            ZMFMA(A0a, A1a, 2);
            ZMFMA(A0b, A1b, 3);

            // splitK slabs to LDS (consumes acc)
            float* slab = red + w * 1024;
            #pragma unroll
            for (int mb = 0; mb < 4; ++mb)
                *(float4v*)&slab[(mb * 64 + lane) * 4] = acc[mb];
        }

        if (projA) {
            float4v pacc = (float4v){0.f, 0.f, 0.f, 0.f};
            pacc = __builtin_amdgcn_mfma_f32_16x16x32_bf16(PAh, PWh, pacc, 0, 0, 0);
            pacc = __builtin_amdgcn_mfma_f32_16x16x32_bf16(PAh, PWl, pacc, 0, 0, 0);
            pacc = __builtin_amdgcn_mfma_f32_16x16x32_bf16(PAl, PWh, pacc, 0, 0, 0);
            *(float4v*)&red2[(w * 64 + lane) * 4] = pacc;
        }

        __syncthreads();

        if (t < NT && tid < 256) {
            // fused splitK reduce + gate math + packed h(t+1) store
            float zi = b_i, zf = b_f, zg = b_g, zo = b_o;
            #pragma unroll
            for (int ww = 0; ww < 8; ++ww) {
                const float* s = red + ww * 1024;
                zi += s[zb]; zf += s[zb + 16]; zg += s[zb + 32]; zo += s[zb + 48];
            }
            float iv = sigf(zi), fv = sigf(zf), gv = tanhf(zg), ov = sigf(zo);
            creg = fv * creg + iv * gv;
            float hv = ov * tanhf(creg);
            float back;
            unsigned short h0 = bf_hi(hv, &back);
            unsigned short h1 = bf_hi(hv - back, &back);
            unsigned v = (unsigned)h0 | ((unsigned)h1 << 16);
            const int base = lane & ~3;                      // 4 cols = 4 consecutive lanes
            unsigned v0 = __shfl(v, base, 64);
            unsigned v1 = __shfl(v, base + 1, 64);
            unsigned v2 = __shfl(v, base + 2, 64);
            unsigned v3 = __shfl(v, base + 3, 64);
            if ((lane & 3) == 0) {
                uint2v hi2, lo2;
                hi2[0] = (v0 & 0xFFFFu) | (v1 << 16);
                hi2[1] = (v2 & 0xFFFFu) | (v3 << 16);
                lo2[0] = (v0 >> 16) | (v1 & 0xFFFF0000u);
                lo2[1] = (v2 >> 16) | (v3 & 0xFFFF0000u);
                unsigned short* hw = hh + (size_t)(t + 1) * HSTEP;
                sc_store_dwordx2(hw + hp, hi2);
                sc_store_dwordx2(hw + hp + 65536, lo2);      // lo plane
            }
        }

        if (projA && tid >= 256) {
            // proj reduce (parallel with gate threads), coalesced store
            const int q = tid - 256;
            const int c = q & 15, rr = (q >> 4) & 3, hb4 = q >> 6;
            const int p = (hb4 * 16 + c) * 4 + rr;
            float s = 0.f;
            #pragma unroll
            for (int ww = 0; ww < 8; ++ww) s += red2[ww * 256 + p];
            const int prow = mbp * 16 + hb4 * 4 + rr;
            const int pcol = nbp * 16 + c;
            sc_store_dword(opart + (size_t)(t & 1) * 65536 + (size_t)kq * 16384
                           + (size_t)prow * NDOUT + pcol, s);
        }

        if (bid < 8 && t >= 2) {
            // ---- out-reduce of opart[(t-1)&1] (4 K-quarters) -> out row t-2 ----
            const float* op = opart + (size_t)((t - 1) & 1) * 65536;
            int idx = bid * 512 + tid;                       // [0,4096)
            int m = idx >> 6, oc4 = (idx & 63) * 4;
            float4v s0, s1, s2, s3;
            LD4(s0, s1, s2, s3,
                &op[(size_t)m * NDOUT + oc4],
                &op[16384 + (size_t)m * NDOUT + oc4],
                &op[32768 + (size_t)m * NDOUT + oc4],
                &op[49152 + (size_t)m * NDOUT + oc4]);
            float4v bv = *(const float4v*)&bo[oc4];
            float4v v = s0 + s1 + s2 + s3 + bv;
            float4v rr;
            rr[0] = fmaxf(v[0], 0.f); rr[1] = fmaxf(v[1], 0.f);
            rr[2] = fmaxf(v[2], 0.f); rr[3] = fmaxf(v[3], 0.f);
            *(float4v*)&out[((size_t)m * NT + (t - 2)) * NDOUT + oc4] = rr;
        }

        gbar_arrive(bar, bid, t);
        if (t + 1 < NT) XPART(t + 1);                        // covers barrier skew
        gbar_wait(bar, bid, t);
    }
}

extern "C" void kernel_launch(void* const* d_in, const int* in_sizes, int n_in,
                              void* d_out, int out_size, void* d_ws, size_t ws_size,
                              hipStream_t stream) {
    const float* x  = (const float*)d_in[0];
    const float* Wx = (const float*)d_in[1];
    const float* Wh = (const float*)d_in[2];
    const float* b  = (const float*)d_in[3];
    const float* Wo = (const float*)d_in[4];
    const float* bo = (const float*)d_in[5];
    float* out = (float*)d_out;
    char* ws = (char*)d_ws;

    const size_t hh_bytes = (size_t)(NT + 1) * HSTEP * 2;    // 513 x 256 KB

    size_t off = 0;
    unsigned* bar = (unsigned*)(ws + off);             off += 40960;  // 256 flag lines + pub
    unsigned short* hh = (unsigned short*)(ws + off);  off += hh_bytes;
    size_t zero_floats = (40960 + (size_t)HSTEP * 2) / 4;     // bar + hh slab0
    float* opart = (float*)(ws + off);                 off += (size_t)2 * 4 * NB * NDOUT * 4;  // 512 KB
    unsigned short* Wzf = (unsigned short*)(ws + off); off += (size_t)1280 * 4096 * 2 * 2;     // 21 MB
    unsigned short* Wo0f = (unsigned short*)(ws + off); off += (size_t)NH * NDOUT * 2;
    unsigned short* Wo1f = (unsigned short*)(ws + off); off += (size_t)NH * NDOUT * 2;
    unsigned short* xf0 = (unsigned short*)(ws + off); off += (size_t)NB * NT * NDIN * 2;
    unsigned short* xf1 = (unsigned short*)(ws + off); off += (size_t)NB * NT * NDIN * 2;

    zero_kernel<<<(int)((zero_floats + 255) / 256), 256, 0, stream>>>((float*)ws, (int)zero_floats);
    packWz_kernel<<<(1280 * 4096 + 255) / 256, 256, 0, stream>>>(Wx, Wh, Wzf);
    packX_kernel<<<(NB * NT * NDIN + 255) / 256, 256, 0, stream>>>(x, xf0, xf1);
    packWo_kernel<<<(NH * NDOUT + 255) / 256, 256, 0, stream>>>(Wo, Wo0f, Wo1f);

    void* args[] = {(void*)&Wzf, (void*)&xf0, (void*)&xf1, (void*)&Wo0f, (void*)&Wo1f,
                    (void*)&hh, (void*)&opart, (void*)&b, (void*)&bo, (void*)&out, (void*)&bar};
    hipLaunchCooperativeKernel((void*)persist_z256_kernel, dim3(GRIDN), dim3(512),
                               args, (unsigned)LDSB, stream);
}

// Round 10
// 4352.788 us; speedup vs baseline: 1.6725x; 1.0493x over previous
//
#include <hip/hip_runtime.h>
#include <hip/hip_bf16.h>
#include <math.h>

#define NB 64
#define NT 512
#define NDIN 256
#define NH 1024
#define NG 4096
#define NDOUT 256

// 256 blocks: ALL do z (4 h-cols each, 8-wave splitK) AND proj (1 tile x K-quarter);
// blocks [0,8) also outred. proj/outred run INSIDE the barrier window.
#define GRIDN 256
#define LDSB 122880        // 80K Wz + 32K red(z) + 8K red2(proj)
#define HSTEP 131072       // shorts per h time-slab: [v(2)][ku(32)][mb(4)][512]

typedef __attribute__((ext_vector_type(8))) short short8;
typedef __attribute__((ext_vector_type(4))) float float4v;
typedef __attribute__((ext_vector_type(2))) unsigned uint2v;

__device__ __forceinline__ float sigf(float v) { return 1.0f / (1.0f + expf(-v)); }

__device__ __forceinline__ unsigned short bf_hi(float v, float* back) {
    __hip_bfloat16 b = __float2bfloat16(v);
    *back = __bfloat162float(b);
    union { __hip_bfloat16 b; unsigned short u; } cv; cv.b = b;
    return cv.u;
}

// ---- device-coherent (LLC) helpers ----
#define LD4(o0,o1,o2,o3,p0,p1,p2,p3)                                             \
  asm volatile("global_load_dwordx4 %0, %4, off sc0 sc1\n\t"                     \
               "global_load_dwordx4 %1, %5, off sc0 sc1\n\t"                     \
               "global_load_dwordx4 %2, %6, off sc0 sc1\n\t"                     \
               "global_load_dwordx4 %3, %7, off sc0 sc1\n\t"                     \
               "s_waitcnt vmcnt(0)"                                              \
               : "=&v"(o0),"=&v"(o1),"=&v"(o2),"=&v"(o3)                         \
               : "v"(p0),"v"(p1),"v"(p2),"v"(p3) : "memory")

__device__ __forceinline__ void sc_store_dword(float* p, float v) {
    asm volatile("global_store_dword %0, %1, off sc0 sc1" :: "v"(p), "v"(v) : "memory");
}
__device__ __forceinline__ void sc_store_dwordx2(unsigned short* p, uint2v v) {
    asm volatile("global_store_dwordx2 %0, %1, off sc0 sc1" :: "v"(p), "v"(v) : "memory");
}

// ---- direct-poll flag barrier (no gather, no publish) ----
// Arrival: block stores epoch t+1 to its own 128B line (after vmcnt drain).
// Wait: every block's threads 0..255 each poll ONE flag line in parallel.
// Serial depth = writer flag store -> reader load (~2 LLC hops).
__device__ __forceinline__ void gbar_arrive(unsigned* bar, int bid, int t) {
    asm volatile("s_waitcnt vmcnt(0)" ::: "memory");   // drain own sc-stores
    __syncthreads();
    if (threadIdx.x == 0)
        __hip_atomic_store(bar + (unsigned)bid * 32, (unsigned)(t + 1),
                           __ATOMIC_RELAXED, __HIP_MEMORY_SCOPE_AGENT);
}

__device__ __forceinline__ void gbar_wait(unsigned* bar, int t) {
    if (threadIdx.x < 256) {
        unsigned* f = bar + (unsigned)threadIdx.x * 32;
        while (__hip_atomic_load(f, __ATOMIC_RELAXED, __HIP_MEMORY_SCOPE_AGENT)
               < (unsigned)(t + 1)) {}
    }
    __syncthreads();
}

__global__ void zero_kernel(float* __restrict__ p, int n) {
    int i = blockIdx.x * 256 + threadIdx.x;
    if (i < n) p[i] = 0.0f;
}

// W (= [Wx;Wh], 1280 x 4096) -> per-block LDS image:
// [jb(256)][ku(40)][plane(2)][lane(64)][j(8)]  (80 KB per jb, contiguous)
__global__ void packWz_kernel(const float* __restrict__ Wx, const float* __restrict__ Wh,
                              unsigned short* __restrict__ Wzf) {
    int e = blockIdx.x * 256 + threadIdx.x;
    if (e >= 1280 * 4096) return;
    int k = e >> 12, col = e & 4095;
    float w = (k < NDIN) ? Wx[(size_t)k * NG + col] : Wh[(size_t)(k - NDIN) * NG + col];
    float back;
    unsigned short w0 = bf_hi(w, &back);
    unsigned short w1 = bf_hi(w - back, &back);
    int g = col >> 10, j = col & 1023;
    int jb = j >> 2, jc = j & 3, n = g * 4 + jc;
    int ku = k >> 5, kr = k & 31;
    int lane = (kr >> 3) * 16 + n, j8 = kr & 7;
    size_t off = ((size_t)jb * 40 + ku) * 1024 + lane * 8 + j8;
    Wzf[off] = w0;          // plane 0 (hi)
    Wzf[off + 512] = w1;    // plane 1 (lo)
}

// x ([64][512][256]) -> A-frag order [t][ku(8)][mb(4)][lane(64)][j(8)], hi/lo
__global__ void packX_kernel(const float* __restrict__ x,
                             unsigned short* __restrict__ xf0, unsigned short* __restrict__ xf1) {
    int e = blockIdx.x * 256 + threadIdx.x;
    if (e >= NB * NT * NDIN) return;
    int k = e & 255, t = (e >> 8) & 511, m = e >> 17;
    float v = x[e];
    float back;
    unsigned short a0 = bf_hi(v, &back);
    unsigned short a1 = bf_hi(v - back, &back);
    int ku = k >> 5, kr = k & 31, mb = m >> 4;
    int lane = (kr >> 3) * 16 + (m & 15), j = kr & 7;
    size_t off = ((((size_t)t * 8 + ku) * 4 + mb) * 64 + lane) * 8 + j;
    xf0[off] = a0; xf1[off] = a1;
}

// Wo (1024 x 256) -> B-frag order [nb(16)][ku(32)][lane(64)][j(8)], hi/lo
__global__ void packWo_kernel(const float* __restrict__ Wo,
                              unsigned short* __restrict__ Wo0f, unsigned short* __restrict__ Wo1f) {
    int e = blockIdx.x * 256 + threadIdx.x;
    if (e >= NH * NDOUT) return;
    int k = e >> 8, n = e & 255;
    float w = Wo[e];
    float back;
    unsigned short w0 = bf_hi(w, &back);
    unsigned short w1 = bf_hi(w - back, &back);
    int nb = n >> 4, nl = n & 15, ku = k >> 5, kr = k & 31;
    int lane = (kr >> 3) * 16 + nl, j = kr & 7;
    size_t off = (((size_t)nb * 32 + ku) * 64 + lane) * 8 + j;
    Wo0f[off] = w0; Wo1f[off] = w1;
}

// z h-load set (one ku = w*4+kk of the h slab): 8 x 16B loads
#define ZLOAD(S0, S1, kk) do {                                                    \
    const unsigned short* _p = hb0 + (size_t)(w4 + (kk)) * 2048 + lane8;          \
    S0[0] = *(const short8*)(_p);        S0[1] = *(const short8*)(_p + 512);      \
    S0[2] = *(const short8*)(_p + 1024); S0[3] = *(const short8*)(_p + 1536);     \
    const unsigned short* _q = _p + 65536;                                        \
    S1[0] = *(const short8*)(_q);        S1[1] = *(const short8*)(_q + 512);      \
    S1[2] = *(const short8*)(_q + 1024); S1[3] = *(const short8*)(_q + 1536);     \
} while (0)

// z MFMA set for one h-ku (3 planes x 4 mb)
#define ZMFMA(S0, S1, kk) do {                                                    \
    const unsigned short* _wp = wlds + (8 + w4 + (kk)) * 1024 + lane8;            \
    short8 _Wh = *(const short8*)(_wp);                                           \
    short8 _Wl = *(const short8*)(_wp + 512);                                     \
    acc[0] = __builtin_amdgcn_mfma_f32_16x16x32_bf16(S0[0], _Wh, acc[0], 0, 0, 0);\
    acc[0] = __builtin_amdgcn_mfma_f32_16x16x32_bf16(S0[0], _Wl, acc[0], 0, 0, 0);\
    acc[0] = __builtin_amdgcn_mfma_f32_16x16x32_bf16(S1[0], _Wh, acc[0], 0, 0, 0);\
    acc[1] = __builtin_amdgcn_mfma_f32_16x16x32_bf16(S0[1], _Wh, acc[1], 0, 0, 0);\
    acc[1] = __builtin_amdgcn_mfma_f32_16x16x32_bf16(S0[1], _Wl, acc[1], 0, 0, 0);\
    acc[1] = __builtin_amdgcn_mfma_f32_16x16x32_bf16(S1[1], _Wh, acc[1], 0, 0, 0);\
    acc[2] = __builtin_amdgcn_mfma_f32_16x16x32_bf16(S0[2], _Wh, acc[2], 0, 0, 0);\
    acc[2] = __builtin_amdgcn_mfma_f32_16x16x32_bf16(S0[2], _Wl, acc[2], 0, 0, 0);\
    acc[2] = __builtin_amdgcn_mfma_f32_16x16x32_bf16(S1[2], _Wh, acc[2], 0, 0, 0);\
    acc[3] = __builtin_amdgcn_mfma_f32_16x16x32_bf16(S0[3], _Wh, acc[3], 0, 0, 0);\
    acc[3] = __builtin_amdgcn_mfma_f32_16x16x32_bf16(S0[3], _Wl, acc[3], 0, 0, 0);\
    acc[3] = __builtin_amdgcn_mfma_f32_16x16x32_bf16(S1[3], _Wh, acc[3], 0, 0, 0);\
} while (0)

// x-partial for step tt: wave's x-ku = w, 4 mb x 3 MFMA, result REPLACES acc
#define XPART(tt) do {                                                            \
    const unsigned short* _xp0 = xf0 + ((size_t)(tt) * 8 + w) * 2048 + lane8;     \
    const unsigned short* _xp1 = xf1 + ((size_t)(tt) * 8 + w) * 2048 + lane8;     \
    short8 _X0[4], _X1[4];                                                        \
    _Pragma("unroll")                                                             \
    for (int _mb = 0; _mb < 4; ++_mb) {                                           \
        _X0[_mb] = *(const short8*)(_xp0 + _mb * 512);                            \
        _X1[_mb] = *(const short8*)(_xp1 + _mb * 512);                            \
    }                                                                             \
    const short8 _Wh = *(const short8*)(wlds + w * 1024 + lane8);                 \
    const short8 _Wl = *(const short8*)(wlds + w * 1024 + 512 + lane8);           \
    _Pragma("unroll")                                                             \
    for (int _mb = 0; _mb < 4; ++_mb) {                                           \
        float4v _a = (float4v){0.f, 0.f, 0.f, 0.f};                               \
        _a = __builtin_amdgcn_mfma_f32_16x16x32_bf16(_X0[_mb], _Wh, _a, 0, 0, 0); \
        _a = __builtin_amdgcn_mfma_f32_16x16x32_bf16(_X0[_mb], _Wl, _a, 0, 0, 0); \
        _a = __builtin_amdgcn_mfma_f32_16x16x32_bf16(_X1[_mb], _Wh, _a, 0, 0, 0); \
        acc[_mb] = _a;                                                            \
    }                                                                             \
} while (0)

// ================= 256-block persistent kernel (r9 + in-window proj/outred) ====
__global__ __launch_bounds__(512, 2) void persist_z256_kernel(
    const unsigned short* __restrict__ Wzf,
    const unsigned short* __restrict__ xf0, const unsigned short* __restrict__ xf1,
    const unsigned short* __restrict__ Wo0f, const unsigned short* __restrict__ Wo1f,
    unsigned short* __restrict__ hh, float* __restrict__ opart,
    const float* __restrict__ bias, const float* __restrict__ bo,
    float* __restrict__ out, unsigned* __restrict__ bar)
{
    extern __shared__ char dynlds[];
    unsigned short* wlds = (unsigned short*)dynlds;          // [40][2][64][8] = 80 KB
    float* red  = (float*)(dynlds + 81920);                  // [8][1024] z splitK slabs
    float* red2 = (float*)(dynlds + 114688);                 // [8][256] proj slabs

    const int bid = blockIdx.x, tid = threadIdx.x;
    const int lane = tid & 63, w = tid >> 6;
    const int lane8 = lane * 8, w4 = w * 4;

    // ---- one-time: W slice -> LDS (80 KB straight copy) ----
    {
        const unsigned short* src = Wzf + (size_t)bid * 40960;
        for (int i = tid; i < 5120; i += 512)
            *(short8*)(wlds + i * 8) = *(const short8*)(src + i * 8);
    }
    __syncthreads();

    // ---- per-thread gate-math constants (threads 0..255 own (row, col)) ----
    const int grow = tid >> 2, gjc = tid & 3;
    const int gj = bid * 4 + gjc;                            // global h-col
    const float b_i = bias[gj], b_f = bias[NH + gj], b_g = bias[2 * NH + gj], b_o = bias[3 * NH + gj];
    const int zb = ((grow >> 4) * 64 + (((grow & 15) >> 2) * 16) + gjc) * 4 + (grow & 3);
    // packed h-store address (4 cols of a row are 4 consecutive shorts)
    const int kuh = bid >> 3, krh3 = (bid & 7) >> 1, j80 = (bid & 1) * 4;
    const size_t hp = ((size_t)(kuh * 4 + (grow >> 4))) * 512
                    + (krh3 * 16 + (grow & 15)) * 8 + j80;
    float creg = 0.0f;                                       // cell state, register-resident

    // ---- proj constants: block owns tile (mbp,nbp) x K-quarter kq; wave owns 1 ku
    const int kq = bid & 3, tt0 = bid >> 2;
    const int mbp = tt0 >> 4, nbp = tt0 & 15;
    const int kup = kq * 8 + w;
    const size_t wo_off = (((size_t)nbp * 32 + kup) * 64 + lane) * 8;
    const short8 PWh = *(const short8*)(Wo0f + wo_off);      // Wo frags loop-invariant
    const short8 PWl = *(const short8*)(Wo1f + wo_off);

    float4v acc[4];
    XPART(0);                                                // prologue: x(0) partial

    for (int t = 0; t <= NT + 2; ++t) {
        const unsigned short* hb0 = hh + (size_t)t * HSTEP;  // h(t) slab, hi plane

        if (t < NT) {
            // ---- z h-part: K=1024 over 4 ku/wave, a/b double-buffered loads ----
            short8 A0a[4], A1a[4], A0b[4], A1b[4];
            ZLOAD(A0a, A1a, 0);
            ZLOAD(A0b, A1b, 1);
            ZMFMA(A0a, A1a, 0);
            ZLOAD(A0a, A1a, 2);
            ZMFMA(A0b, A1b, 1);
            ZLOAD(A0b, A1b, 3);
            ZMFMA(A0a, A1a, 2);
            ZMFMA(A0b, A1b, 3);

            // splitK slabs to LDS (consumes acc)
            float* slab = red + w * 1024;
            #pragma unroll
            for (int mb = 0; mb < 4; ++mb)
                *(float4v*)&slab[(mb * 64 + lane) * 4] = acc[mb];

            __syncthreads();

            if (tid < 256) {
                // fused splitK reduce + gate math + packed h(t+1) store
                float zi = b_i, zf = b_f, zg = b_g, zo = b_o;
                #pragma unroll
                for (int ww = 0; ww < 8; ++ww) {
                    const float* s = red + ww * 1024;
                    zi += s[zb]; zf += s[zb + 16]; zg += s[zb + 32]; zo += s[zb + 48];
                }
                float iv = sigf(zi), fv = sigf(zf), gv = tanhf(zg), ov = sigf(zo);
                creg = fv * creg + iv * gv;
                float hv = ov * tanhf(creg);
                float back;
                unsigned short h0 = bf_hi(hv, &back);
                unsigned short h1 = bf_hi(hv - back, &back);
                unsigned v = (unsigned)h0 | ((unsigned)h1 << 16);
                const int base = lane & ~3;                  // 4 cols = 4 consecutive lanes
                unsigned v0 = __shfl(v, base, 64);
                unsigned v1 = __shfl(v, base + 1, 64);
                unsigned v2 = __shfl(v, base + 2, 64);
                unsigned v3 = __shfl(v, base + 3, 64);
                if ((lane & 3) == 0) {
                    uint2v hi2, lo2;
                    hi2[0] = (v0 & 0xFFFFu) | (v1 << 16);
                    hi2[1] = (v2 & 0xFFFFu) | (v3 << 16);
                    lo2[0] = (v0 >> 16) | (v1 & 0xFFFF0000u);
                    lo2[1] = (v2 >> 16) | (v3 & 0xFFFF0000u);
                    unsigned short* hw = hh + (size_t)(t + 1) * HSTEP;
                    sc_store_dwordx2(hw + hp, hi2);
                    sc_store_dwordx2(hw + hp + 65536, lo2);  // lo plane
                }
            }
        }

        gbar_arrive(bar, bid, t);

        // ======== overlap window: work not needed by OTHER blocks this step ====
        const int projA = (t >= 1 && t <= NT);
        short8 PAh, PAl;
        if (projA) {
            // proj A loads issued first (h(t) stable since barrier t-1)
            const unsigned short* ap = hb0 + (size_t)(kup * 4 + mbp) * 512 + lane8;
            PAh = *(const short8*)ap;
            PAl = *(const short8*)(ap + 65536);
        }

        if (t + 1 < NT) XPART(t + 1);                        // next-step x partial

        if (projA) {
            float4v pacc = (float4v){0.f, 0.f, 0.f, 0.f};
            pacc = __builtin_amdgcn_mfma_f32_16x16x32_bf16(PAh, PWh, pacc, 0, 0, 0);
            pacc = __builtin_amdgcn_mfma_f32_16x16x32_bf16(PAh, PWl, pacc, 0, 0, 0);
            pacc = __builtin_amdgcn_mfma_f32_16x16x32_bf16(PAl, PWh, pacc, 0, 0, 0);
            *(float4v*)&red2[(w * 64 + lane) * 4] = pacc;
            __syncthreads();
            if (tid < 256) {
                // proj reduce, coalesced store into 4-slab opart ring (slab t&3)
                const int c = tid & 15, rr = (tid >> 4) & 3, hb4 = tid >> 6;
                const int p = (hb4 * 16 + c) * 4 + rr;
                float s = 0.f;
                #pragma unroll
                for (int ww = 0; ww < 8; ++ww) s += red2[ww * 256 + p];
                const int prow = mbp * 16 + hb4 * 4 + rr;
                const int pcol = nbp * 16 + c;
                sc_store_dword(opart + (size_t)(t & 3) * 65536 + (size_t)kq * 16384
                               + (size_t)prow * NDOUT + pcol, s);
            }
        }

        if (bid < 8 && t >= 3) {
            // ---- outred: opart slab (t-2)&3 (proj of h step t-3) -> out row t-3 ----
            const float* op = opart + (size_t)((t - 2) & 3) * 65536;
            int idx = bid * 512 + tid;                       // [0,4096)
            int m = idx >> 6, oc4 = (idx & 63) * 4;
            float4v s0, s1, s2, s3;
            LD4(s0, s1, s2, s3,
                &op[(size_t)m * NDOUT + oc4],
                &op[16384 + (size_t)m * NDOUT + oc4],
                &op[32768 + (size_t)m * NDOUT + oc4],
                &op[49152 + (size_t)m * NDOUT + oc4]);
            float4v bv = *(const float4v*)&bo[oc4];
            float4v v = s0 + s1 + s2 + s3 + bv;
            float4v rr;
            rr[0] = fmaxf(v[0], 0.f); rr[1] = fmaxf(v[1], 0.f);
            rr[2] = fmaxf(v[2], 0.f); rr[3] = fmaxf(v[3], 0.f);
            *(float4v*)&out[((size_t)m * NT + (t - 3)) * NDOUT + oc4] = rr;
        }

        gbar_wait(bar, t);
    }
}

extern "C" void kernel_launch(void* const* d_in, const int* in_sizes, int n_in,
                              void* d_out, int out_size, void* d_ws, size_t ws_size,
                              hipStream_t stream) {
    const float* x  = (const float*)d_in[0];
    const float* Wx = (const float*)d_in[1];
    const float* Wh = (const float*)d_in[2];
    const float* b  = (const float*)d_in[3];
    const float* Wo = (const float*)d_in[4];
    const float* bo = (const float*)d_in[5];
    float* out = (float*)d_out;
    char* ws = (char*)d_ws;

    const size_t hh_bytes = (size_t)(NT + 3) * HSTEP * 2;    // 515 x 256 KB

    size_t off = 0;
    unsigned* bar = (unsigned*)(ws + off);             off += 32768;  // 256 flag lines
    unsigned short* hh = (unsigned short*)(ws + off);  off += hh_bytes;
    size_t zero_floats = (32768 + (size_t)HSTEP * 2) / 4;     // bar + hh slab0
    float* opart = (float*)(ws + off);                 off += (size_t)4 * 4 * NB * NDOUT * 4;  // 1 MB ring
    unsigned short* Wzf = (unsigned short*)(ws + off); off += (size_t)1280 * 4096 * 2 * 2;     // 21 MB
    unsigned short* Wo0f = (unsigned short*)(ws + off); off += (size_t)NH * NDOUT * 2;
    unsigned short* Wo1f = (unsigned short*)(ws + off); off += (size_t)NH * NDOUT * 2;
    unsigned short* xf0 = (unsigned short*)(ws + off); off += (size_t)NB * NT * NDIN * 2;
    unsigned short* xf1 = (unsigned short*)(ws + off); off += (size_t)NB * NT * NDIN * 2;

    zero_kernel<<<(int)((zero_floats + 255) / 256), 256, 0, stream>>>((float*)ws, (int)zero_floats);
    packWz_kernel<<<(1280 * 4096 + 255) / 256, 256, 0, stream>>>(Wx, Wh, Wzf);
    packX_kernel<<<(NB * NT * NDIN + 255) / 256, 256, 0, stream>>>(x, xf0, xf1);
    packWo_kernel<<<(NH * NDOUT + 255) / 256, 256, 0, stream>>>(Wo, Wo0f, Wo1f);

    void* args[] = {(void*)&Wzf, (void*)&xf0, (void*)&xf1, (void*)&Wo0f, (void*)&Wo1f,
                    (void*)&hh, (void*)&opart, (void*)&b, (void*)&bo, (void*)&out, (void*)&bar};
    hipLaunchCooperativeKernel((void*)persist_z256_kernel, dim3(GRIDN), dim3(512),
                               args, (unsigned)LDSB, stream);
}

// Round 11
// 4143.783 us; speedup vs baseline: 1.7569x; 1.0504x over previous
//
#include <hip/hip_runtime.h>
#include <hip/hip_bf16.h>
#include <math.h>

#define NB 64
#define NT 512
#define NDIN 256
#define NH 1024
#define NG 4096
#define NDOUT 256

// 256 blocks: ALL do z (4 h-cols each, 8-wave splitK) AND proj (1 tile x K-quarter);
// blocks [0,8) also outred. proj/outred run INSIDE the barrier window.
#define GRIDN 256
#define LDSB 122880        // 80K Wz + 32K red(z) + 8K red2(proj)
#define HSTEP 131072       // shorts per h time-slab: [v(2)][ku(32)][mb(4)][512]

typedef __attribute__((ext_vector_type(8))) short short8;
typedef __attribute__((ext_vector_type(4))) float float4v;
typedef __attribute__((ext_vector_type(2))) unsigned uint2v;

__device__ __forceinline__ float sigf(float v) { return 1.0f / (1.0f + expf(-v)); }

__device__ __forceinline__ unsigned short bf_hi(float v, float* back) {
    __hip_bfloat16 b = __float2bfloat16(v);
    *back = __bfloat162float(b);
    union { __hip_bfloat16 b; unsigned short u; } cv; cv.b = b;
    return cv.u;
}

// ---- device-coherent (LLC) helpers ----
#define LD4(o0,o1,o2,o3,p0,p1,p2,p3)                                             \
  asm volatile("global_load_dwordx4 %0, %4, off sc0 sc1\n\t"                     \
               "global_load_dwordx4 %1, %5, off sc0 sc1\n\t"                     \
               "global_load_dwordx4 %2, %6, off sc0 sc1\n\t"                     \
               "global_load_dwordx4 %3, %7, off sc0 sc1\n\t"                     \
               "s_waitcnt vmcnt(0)"                                              \
               : "=&v"(o0),"=&v"(o1),"=&v"(o2),"=&v"(o3)                         \
               : "v"(p0),"v"(p1),"v"(p2),"v"(p3) : "memory")

__device__ __forceinline__ void sc_store_dword(float* p, float v) {
    asm volatile("global_store_dword %0, %1, off sc0 sc1" :: "v"(p), "v"(v) : "memory");
}
__device__ __forceinline__ void sc_store_dwordx2(unsigned short* p, uint2v v) {
    asm volatile("global_store_dwordx2 %0, %1, off sc0 sc1" :: "v"(p), "v"(v) : "memory");
}

// ---- compact-flag barrier: 16B-stride flags, single-wave polling ----
// Arrival: block stores epoch t+1 to its flag (16B stride -> 8 writers/line,
// 32 lines total). Wait: wave 0 only; lane L polls blocks L,L+64,L+128,L+192
// (4 independent loads/iter). __syncthreads releases the other waves.
// Monotonic epochs -> no reset race.
__device__ __forceinline__ void gbar_arrive(unsigned* bar, int bid, int t) {
    asm volatile("s_waitcnt vmcnt(0)" ::: "memory");   // drain own sc-stores
    __syncthreads();
    if (threadIdx.x == 0)
        __hip_atomic_store(bar + (unsigned)bid * 4, (unsigned)(t + 1),
                           __ATOMIC_RELAXED, __HIP_MEMORY_SCOPE_AGENT);
}

__device__ __forceinline__ void gbar_wait(unsigned* bar, int t) {
    if (threadIdx.x < 64) {
        const unsigned tgt = (unsigned)(t + 1);
        unsigned* f = bar + threadIdx.x * 4;
        for (;;) {
            unsigned v0 = __hip_atomic_load(f,           __ATOMIC_RELAXED, __HIP_MEMORY_SCOPE_AGENT);
            unsigned v1 = __hip_atomic_load(f + 256,     __ATOMIC_RELAXED, __HIP_MEMORY_SCOPE_AGENT);
            unsigned v2 = __hip_atomic_load(f + 512,     __ATOMIC_RELAXED, __HIP_MEMORY_SCOPE_AGENT);
            unsigned v3 = __hip_atomic_load(f + 768,     __ATOMIC_RELAXED, __HIP_MEMORY_SCOPE_AGENT);
            unsigned mn = min(min(v0, v1), min(v2, v3));
            if (__all(mn >= tgt)) break;
        }
    }
    __syncthreads();
}

__global__ void zero_kernel(float* __restrict__ p, int n) {
    int i = blockIdx.x * 256 + threadIdx.x;
    if (i < n) p[i] = 0.0f;
}

// W (= [Wx;Wh], 1280 x 4096) -> per-block LDS image:
// [jb(256)][ku(40)][plane(2)][lane(64)][j(8)]  (80 KB per jb, contiguous)
__global__ void packWz_kernel(const float* __restrict__ Wx, const float* __restrict__ Wh,
                              unsigned short* __restrict__ Wzf) {
    int e = blockIdx.x * 256 + threadIdx.x;
    if (e >= 1280 * 4096) return;
    int k = e >> 12, col = e & 4095;
    float w = (k < NDIN) ? Wx[(size_t)k * NG + col] : Wh[(size_t)(k - NDIN) * NG + col];
    float back;
    unsigned short w0 = bf_hi(w, &back);
    unsigned short w1 = bf_hi(w - back, &back);
    int g = col >> 10, j = col & 1023;
    int jb = j >> 2, jc = j & 3, n = g * 4 + jc;
    int ku = k >> 5, kr = k & 31;
    int lane = (kr >> 3) * 16 + n, j8 = kr & 7;
    size_t off = ((size_t)jb * 40 + ku) * 1024 + lane * 8 + j8;
    Wzf[off] = w0;          // plane 0 (hi)
    Wzf[off + 512] = w1;    // plane 1 (lo)
}

// x ([64][512][256]) -> A-frag order [t][ku(8)][mb(4)][lane(64)][j(8)], hi/lo
__global__ void packX_kernel(const float* __restrict__ x,
                             unsigned short* __restrict__ xf0, unsigned short* __restrict__ xf1) {
    int e = blockIdx.x * 256 + threadIdx.x;
    if (e >= NB * NT * NDIN) return;
    int k = e & 255, t = (e >> 8) & 511, m = e >> 17;
    float v = x[e];
    float back;
    unsigned short a0 = bf_hi(v, &back);
    unsigned short a1 = bf_hi(v - back, &back);
    int ku = k >> 5, kr = k & 31, mb = m >> 4;
    int lane = (kr >> 3) * 16 + (m & 15), j = kr & 7;
    size_t off = ((((size_t)t * 8 + ku) * 4 + mb) * 64 + lane) * 8 + j;
    xf0[off] = a0; xf1[off] = a1;
}

// Wo (1024 x 256) -> B-frag order [nb(16)][ku(32)][lane(64)][j(8)], hi/lo
__global__ void packWo_kernel(const float* __restrict__ Wo,
                              unsigned short* __restrict__ Wo0f, unsigned short* __restrict__ Wo1f) {
    int e = blockIdx.x * 256 + threadIdx.x;
    if (e >= NH * NDOUT) return;
    int k = e >> 8, n = e & 255;
    float w = Wo[e];
    float back;
    unsigned short w0 = bf_hi(w, &back);
    unsigned short w1 = bf_hi(w - back, &back);
    int nb = n >> 4, nl = n & 15, ku = k >> 5, kr = k & 31;
    int lane = (kr >> 3) * 16 + nl, j = kr & 7;
    size_t off = (((size_t)nb * 32 + ku) * 64 + lane) * 8 + j;
    Wo0f[off] = w0; Wo1f[off] = w1;
}

// z h-load set (one ku = w*4+kk of the h slab): 8 x 16B loads
#define ZLOAD(S0, S1, kk) do {                                                    \
    const unsigned short* _p = hb0 + (size_t)(w4 + (kk)) * 2048 + lane8;          \
    S0[0] = *(const short8*)(_p);        S0[1] = *(const short8*)(_p + 512);      \
    S0[2] = *(const short8*)(_p + 1024); S0[3] = *(const short8*)(_p + 1536);     \
    const unsigned short* _q = _p + 65536;                                        \
    S1[0] = *(const short8*)(_q);        S1[1] = *(const short8*)(_q + 512);      \
    S1[2] = *(const short8*)(_q + 1024); S1[3] = *(const short8*)(_q + 1536);     \
} while (0)

// z MFMA set for one h-ku (3 planes x 4 mb)
#define ZMFMA(S0, S1, kk) do {                                                    \
    const unsigned short* _wp = wlds + (8 + w4 + (kk)) * 1024 + lane8;            \
    short8 _Wh = *(const short8*)(_wp);                                           \
    short8 _Wl = *(const short8*)(_wp + 512);                                     \
    acc[0] = __builtin_amdgcn_mfma_f32_16x16x32_bf16(S0[0], _Wh, acc[0], 0, 0, 0);\
    acc[0] = __builtin_amdgcn_mfma_f32_16x16x32_bf16(S0[0], _Wl, acc[0], 0, 0, 0);\
    acc[0] = __builtin_amdgcn_mfma_f32_16x16x32_bf16(S1[0], _Wh, acc[0], 0, 0, 0);\
    acc[1] = __builtin_amdgcn_mfma_f32_16x16x32_bf16(S0[1], _Wh, acc[1], 0, 0, 0);\
    acc[1] = __builtin_amdgcn_mfma_f32_16x16x32_bf16(S0[1], _Wl, acc[1], 0, 0, 0);\
    acc[1] = __builtin_amdgcn_mfma_f32_16x16x32_bf16(S1[1], _Wh, acc[1], 0, 0, 0);\
    acc[2] = __builtin_amdgcn_mfma_f32_16x16x32_bf16(S0[2], _Wh, acc[2], 0, 0, 0);\
    acc[2] = __builtin_amdgcn_mfma_f32_16x16x32_bf16(S0[2], _Wl, acc[2], 0, 0, 0);\
    acc[2] = __builtin_amdgcn_mfma_f32_16x16x32_bf16(S1[2], _Wh, acc[2], 0, 0, 0);\
    acc[3] = __builtin_amdgcn_mfma_f32_16x16x32_bf16(S0[3], _Wh, acc[3], 0, 0, 0);\
    acc[3] = __builtin_amdgcn_mfma_f32_16x16x32_bf16(S0[3], _Wl, acc[3], 0, 0, 0);\
    acc[3] = __builtin_amdgcn_mfma_f32_16x16x32_bf16(S1[3], _Wh, acc[3], 0, 0, 0);\
} while (0)

// x-partial for step tt: wave's x-ku = w, 4 mb x 3 MFMA, result REPLACES acc
#define XPART(tt) do {                                                            \
    const unsigned short* _xp0 = xf0 + ((size_t)(tt) * 8 + w) * 2048 + lane8;     \
    const unsigned short* _xp1 = xf1 + ((size_t)(tt) * 8 + w) * 2048 + lane8;     \
    short8 _X0[4], _X1[4];                                                        \
    _Pragma("unroll")                                                             \
    for (int _mb = 0; _mb < 4; ++_mb) {                                           \
        _X0[_mb] = *(const short8*)(_xp0 + _mb * 512);                            \
        _X1[_mb] = *(const short8*)(_xp1 + _mb * 512);                            \
    }                                                                             \
    const short8 _Wh = *(const short8*)(wlds + w * 1024 + lane8);                 \
    const short8 _Wl = *(const short8*)(wlds + w * 1024 + 512 + lane8);           \
    _Pragma("unroll")                                                             \
    for (int _mb = 0; _mb < 4; ++_mb) {                                           \
        float4v _a = (float4v){0.f, 0.f, 0.f, 0.f};                               \
        _a = __builtin_amdgcn_mfma_f32_16x16x32_bf16(_X0[_mb], _Wh, _a, 0, 0, 0); \
        _a = __builtin_amdgcn_mfma_f32_16x16x32_bf16(_X0[_mb], _Wl, _a, 0, 0, 0); \
        _a = __builtin_amdgcn_mfma_f32_16x16x32_bf16(_X1[_mb], _Wh, _a, 0, 0, 0); \
        acc[_mb] = _a;                                                            \
    }                                                                             \
} while (0)

// ================= 256-block persistent kernel (r10 + poll fix + load hoist) ===
__global__ __launch_bounds__(512, 2) void persist_z256_kernel(
    const unsigned short* __restrict__ Wzf,
    const unsigned short* __restrict__ xf0, const unsigned short* __restrict__ xf1,
    const unsigned short* __restrict__ Wo0f, const unsigned short* __restrict__ Wo1f,
    unsigned short* __restrict__ hh, float* __restrict__ opart,
    const float* __restrict__ bias, const float* __restrict__ bo,
    float* __restrict__ out, unsigned* __restrict__ bar)
{
    extern __shared__ char dynlds[];
    unsigned short* wlds = (unsigned short*)dynlds;          // [40][2][64][8] = 80 KB
    float* red  = (float*)(dynlds + 81920);                  // [8][1024] z splitK slabs
    float* red2 = (float*)(dynlds + 114688);                 // [8][256] proj slabs

    const int bid = blockIdx.x, tid = threadIdx.x;
    const int lane = tid & 63, w = tid >> 6;
    const int lane8 = lane * 8, w4 = w * 4;

    // ---- one-time: W slice -> LDS (80 KB straight copy) ----
    {
        const unsigned short* src = Wzf + (size_t)bid * 40960;
        for (int i = tid; i < 5120; i += 512)
            *(short8*)(wlds + i * 8) = *(const short8*)(src + i * 8);
    }
    __syncthreads();

    // ---- per-thread gate-math constants (threads 0..255 own (row, col)) ----
    const int grow = tid >> 2, gjc = tid & 3;
    const int gj = bid * 4 + gjc;                            // global h-col
    const float b_i = bias[gj], b_f = bias[NH + gj], b_g = bias[2 * NH + gj], b_o = bias[3 * NH + gj];
    const int zb = ((grow >> 4) * 64 + (((grow & 15) >> 2) * 16) + gjc) * 4 + (grow & 3);
    // packed h-store address (4 cols of a row are 4 consecutive shorts)
    const int kuh = bid >> 3, krh3 = (bid & 7) >> 1, j80 = (bid & 1) * 4;
    const size_t hp = ((size_t)(kuh * 4 + (grow >> 4))) * 512
                    + (krh3 * 16 + (grow & 15)) * 8 + j80;
    float creg = 0.0f;                                       // cell state, register-resident

    // ---- proj constants: block owns tile (mbp,nbp) x K-quarter kq; wave owns 1 ku
    const int kq = bid & 3, tt0 = bid >> 2;
    const int mbp = tt0 >> 4, nbp = tt0 & 15;
    const int kup = kq * 8 + w;
    const size_t wo_off = (((size_t)nbp * 32 + kup) * 64 + lane) * 8;
    const short8 PWh = *(const short8*)(Wo0f + wo_off);      // Wo frags loop-invariant
    const short8 PWl = *(const short8*)(Wo1f + wo_off);

    float4v acc[4];
    XPART(0);                                                // prologue: x(0) partial

    for (int t = 0; t <= NT + 2; ++t) {
        const unsigned short* hb0 = hh + (size_t)t * HSTEP;  // h(t) slab, hi plane

        if (t < NT) {
            // ---- z h-part: all 4 ku load-sets issued BEFORE any MFMA (full MLP) ----
            short8 A0[4][4], A1[4][4];
            ZLOAD(A0[0], A1[0], 0);
            ZLOAD(A0[1], A1[1], 1);
            ZLOAD(A0[2], A1[2], 2);
            ZLOAD(A0[3], A1[3], 3);
            ZMFMA(A0[0], A1[0], 0);
            ZMFMA(A0[1], A1[1], 1);
            ZMFMA(A0[2], A1[2], 2);
            ZMFMA(A0[3], A1[3], 3);

            // splitK slabs to LDS (consumes acc)
            float* slab = red + w * 1024;
            #pragma unroll
            for (int mb = 0; mb < 4; ++mb)
                *(float4v*)&slab[(mb * 64 + lane) * 4] = acc[mb];

            __syncthreads();

            if (tid < 256) {
                // fused splitK reduce + gate math + packed h(t+1) store
                float zi = b_i, zf = b_f, zg = b_g, zo = b_o;
                #pragma unroll
                for (int ww = 0; ww < 8; ++ww) {
                    const float* s = red + ww * 1024;
                    zi += s[zb]; zf += s[zb + 16]; zg += s[zb + 32]; zo += s[zb + 48];
                }
                float iv = sigf(zi), fv = sigf(zf), gv = tanhf(zg), ov = sigf(zo);
                creg = fv * creg + iv * gv;
                float hv = ov * tanhf(creg);
                float back;
                unsigned short h0 = bf_hi(hv, &back);
                unsigned short h1 = bf_hi(hv - back, &back);
                unsigned v = (unsigned)h0 | ((unsigned)h1 << 16);
                const int base = lane & ~3;                  // 4 cols = 4 consecutive lanes
                unsigned v0 = __shfl(v, base, 64);
                unsigned v1 = __shfl(v, base + 1, 64);
                unsigned v2 = __shfl(v, base + 2, 64);
                unsigned v3 = __shfl(v, base + 3, 64);
                if ((lane & 3) == 0) {
                    uint2v hi2, lo2;
                    hi2[0] = (v0 & 0xFFFFu) | (v1 << 16);
                    hi2[1] = (v2 & 0xFFFFu) | (v3 << 16);
                    lo2[0] = (v0 >> 16) | (v1 & 0xFFFF0000u);
                    lo2[1] = (v2 >> 16) | (v3 & 0xFFFF0000u);
                    unsigned short* hw = hh + (size_t)(t + 1) * HSTEP;
                    sc_store_dwordx2(hw + hp, hi2);
                    sc_store_dwordx2(hw + hp + 65536, lo2);  // lo plane
                }
            }
        }

        gbar_arrive(bar, bid, t);

        // ======== overlap window: work not needed by OTHER blocks this step ====
        const int projA = (t >= 1 && t <= NT);
        short8 PAh, PAl;
        if (projA) {
            // proj A loads issued first (h(t) stable since barrier t-1)
            const unsigned short* ap = hb0 + (size_t)(kup * 4 + mbp) * 512 + lane8;
            PAh = *(const short8*)ap;
            PAl = *(const short8*)(ap + 65536);
        }

        if (t + 1 < NT) XPART(t + 1);                        // next-step x partial

        if (projA) {
            float4v pacc = (float4v){0.f, 0.f, 0.f, 0.f};
            pacc = __builtin_amdgcn_mfma_f32_16x16x32_bf16(PAh, PWh, pacc, 0, 0, 0);
            pacc = __builtin_amdgcn_mfma_f32_16x16x32_bf16(PAh, PWl, pacc, 0, 0, 0);
            pacc = __builtin_amdgcn_mfma_f32_16x16x32_bf16(PAl, PWh, pacc, 0, 0, 0);
            *(float4v*)&red2[(w * 64 + lane) * 4] = pacc;
            __syncthreads();
            if (tid < 256) {
                // proj reduce, coalesced store into 4-slab opart ring (slab t&3)
                const int c = tid & 15, rr = (tid >> 4) & 3, hb4 = tid >> 6;
                const int p = (hb4 * 16 + c) * 4 + rr;
                float s = 0.f;
                #pragma unroll
                for (int ww = 0; ww < 8; ++ww) s += red2[ww * 256 + p];
                const int prow = mbp * 16 + hb4 * 4 + rr;
                const int pcol = nbp * 16 + c;
                sc_store_dword(opart + (size_t)(t & 3) * 65536 + (size_t)kq * 16384
                               + (size_t)prow * NDOUT + pcol, s);
            }
        }

        if (bid < 8 && t >= 3) {
            // ---- outred: opart slab (t-2)&3 (proj of h step t-3) -> out row t-3 ----
            const float* op = opart + (size_t)((t - 2) & 3) * 65536;
            int idx = bid * 512 + tid;                       // [0,4096)
            int m = idx >> 6, oc4 = (idx & 63) * 4;
            float4v s0, s1, s2, s3;
            LD4(s0, s1, s2, s3,
                &op[(size_t)m * NDOUT + oc4],
                &op[16384 + (size_t)m * NDOUT + oc4],
                &op[32768 + (size_t)m * NDOUT + oc4],
                &op[49152 + (size_t)m * NDOUT + oc4]);
            float4v bv = *(const float4v*)&bo[oc4];
            float4v v = s0 + s1 + s2 + s3 + bv;
            float4v rr;
            rr[0] = fmaxf(v[0], 0.f); rr[1] = fmaxf(v[1], 0.f);
            rr[2] = fmaxf(v[2], 0.f); rr[3] = fmaxf(v[3], 0.f);
            *(float4v*)&out[((size_t)m * NT + (t - 3)) * NDOUT + oc4] = rr;
        }

        gbar_wait(bar, t);
    }
}

extern "C" void kernel_launch(void* const* d_in, const int* in_sizes, int n_in,
                              void* d_out, int out_size, void* d_ws, size_t ws_size,
                              hipStream_t stream) {
    const float* x  = (const float*)d_in[0];
    const float* Wx = (const float*)d_in[1];
    const float* Wh = (const float*)d_in[2];
    const float* b  = (const float*)d_in[3];
    const float* Wo = (const float*)d_in[4];
    const float* bo = (const float*)d_in[5];
    float* out = (float*)d_out;
    char* ws = (char*)d_ws;

    const size_t hh_bytes = (size_t)(NT + 3) * HSTEP * 2;    // 515 x 256 KB

    size_t off = 0;
    unsigned* bar = (unsigned*)(ws + off);             off += 4096;   // 256 flags @16B stride
    unsigned short* hh = (unsigned short*)(ws + off);  off += hh_bytes;
    size_t zero_floats = (4096 + (size_t)HSTEP * 2) / 4;      // bar + hh slab0
    float* opart = (float*)(ws + off);                 off += (size_t)4 * 4 * NB * NDOUT * 4;  // 1 MB ring
    unsigned short* Wzf = (unsigned short*)(ws + off); off += (size_t)1280 * 4096 * 2 * 2;     // 21 MB
    unsigned short* Wo0f = (unsigned short*)(ws + off); off += (size_t)NH * NDOUT * 2;
    unsigned short* Wo1f = (unsigned short*)(ws + off); off += (size_t)NH * NDOUT * 2;
    unsigned short* xf0 = (unsigned short*)(ws + off); off += (size_t)NB * NT * NDIN * 2;
    unsigned short* xf1 = (unsigned short*)(ws + off); off += (size_t)NB * NT * NDIN * 2;

    zero_kernel<<<(int)((zero_floats + 255) / 256), 256, 0, stream>>>((float*)ws, (int)zero_floats);
    packWz_kernel<<<(1280 * 4096 + 255) / 256, 256, 0, stream>>>(Wx, Wh, Wzf);
    packX_kernel<<<(NB * NT * NDIN + 255) / 256, 256, 0, stream>>>(x, xf0, xf1);
    packWo_kernel<<<(NH * NDOUT + 255) / 256, 256, 0, stream>>>(Wo, Wo0f, Wo1f);

    void* args[] = {(void*)&Wzf, (void*)&xf0, (void*)&xf1, (void*)&Wo0f, (void*)&Wo1f,
                    (void*)&hh, (void*)&opart, (void*)&b, (void*)&bo, (void*)&out, (void*)&bar};
    hipLaunchCooperativeKernel((void*)persist_z256_kernel, dim3(GRIDN), dim3(512),
                               args, (unsigned)LDSB, stream);
}

// Round 12
// 3145.902 us; speedup vs baseline: 2.3141x; 1.3172x over previous
//
#include <hip/hip_runtime.h>
#include <hip/hip_bf16.h>
#include <math.h>

#define NB 64
#define NT 512
#define NDIN 256
#define NH 1024
#define NG 4096
#define NDOUT 256

// 256 blocks: ALL do z (4 h-cols each, 8-wave splitK) AND proj (1 tile x K-quarter);
// blocks [0,8) also outred. NO global barrier in steady state: z-waves poll the
// 8-producer flag line of each h-ku just before loading it (dataflow sync).
#define GRIDN 256
#define LDSB 122880        // 80K Wz + 32K red(z) + 8K red2(proj)
#define HSTEP 131072       // shorts per h time-slab: [v(2)][ku(32)][mb(4)][512]

typedef __attribute__((ext_vector_type(8))) short short8;
typedef __attribute__((ext_vector_type(4))) float float4v;
typedef __attribute__((ext_vector_type(2))) unsigned uint2v;

__device__ __forceinline__ float sigf(float v) { return 1.0f / (1.0f + expf(-v)); }

__device__ __forceinline__ unsigned short bf_hi(float v, float* back) {
    __hip_bfloat16 b = __float2bfloat16(v);
    *back = __bfloat162float(b);
    union { __hip_bfloat16 b; unsigned short u; } cv; cv.b = b;
    return cv.u;
}

// ---- device-coherent (LLC) helpers ----
#define LD4(o0,o1,o2,o3,p0,p1,p2,p3)                                             \
  asm volatile("global_load_dwordx4 %0, %4, off sc0 sc1\n\t"                     \
               "global_load_dwordx4 %1, %5, off sc0 sc1\n\t"                     \
               "global_load_dwordx4 %2, %6, off sc0 sc1\n\t"                     \
               "global_load_dwordx4 %3, %7, off sc0 sc1\n\t"                     \
               "s_waitcnt vmcnt(0)"                                              \
               : "=&v"(o0),"=&v"(o1),"=&v"(o2),"=&v"(o3)                         \
               : "v"(p0),"v"(p1),"v"(p2),"v"(p3) : "memory")

__device__ __forceinline__ void sc_store_dword(float* p, float v) {
    asm volatile("global_store_dword %0, %1, off sc0 sc1" :: "v"(p), "v"(v) : "memory");
}
__device__ __forceinline__ void sc_store_dwordx2(unsigned short* p, uint2v v) {
    asm volatile("global_store_dwordx2 %0, %1, off sc0 sc1" :: "v"(p), "v"(v) : "memory");
}

// ---- flags: one per block, 16B stride. Flag value t+1 means: this block's
// h(t+1) stores AND all its stores from iterations <= t-1 (incl. proj(t-1))
// have drained to the LLC (vmcnt(0) precedes every flag store).
__device__ __forceinline__ void flag_arrive(unsigned* bar, int bid, int t) {
    asm volatile("s_waitcnt vmcnt(0)" ::: "memory");   // drain ALL own sc-stores
    __syncthreads();                                   // all waves' stores drained
    if (threadIdx.x == 0)
        __hip_atomic_store(bar + (unsigned)bid * 4, (unsigned)(t + 1),
                           __ATOMIC_RELAXED, __HIP_MEMORY_SCOPE_AGENT);
}

// per-ku producer poll: the 8 producers of ku u have flags at one 128B line.
// All 64 lanes load the line (lane&7 selects the flag); break when all >= tgt.
#define KUPOLL(kk, tgt) do {                                                      \
    unsigned* _f = bar + (((unsigned)(w4 + (kk))) * 8 + (lane & 7)) * 4;          \
    for (;;) {                                                                    \
        unsigned _v = __hip_atomic_load(_f, __ATOMIC_RELAXED,                     \
                                        __HIP_MEMORY_SCOPE_AGENT);                \
        if (__all(_v >= (unsigned)(tgt))) break;                                  \
    }                                                                             \
    asm volatile("" ::: "memory");                                                \
} while (0)

// full wait (tail iterations only): wave 0 polls all 256 flags >= tgt
__device__ __forceinline__ void wait_full(unsigned* bar, int tgt) {
    if (threadIdx.x < 64) {
        unsigned* f = bar + threadIdx.x * 4;
        for (;;) {
            unsigned v0 = __hip_atomic_load(f,       __ATOMIC_RELAXED, __HIP_MEMORY_SCOPE_AGENT);
            unsigned v1 = __hip_atomic_load(f + 256, __ATOMIC_RELAXED, __HIP_MEMORY_SCOPE_AGENT);
            unsigned v2 = __hip_atomic_load(f + 512, __ATOMIC_RELAXED, __HIP_MEMORY_SCOPE_AGENT);
            unsigned v3 = __hip_atomic_load(f + 768, __ATOMIC_RELAXED, __HIP_MEMORY_SCOPE_AGENT);
            unsigned mn = min(min(v0, v1), min(v2, v3));
            if (__all(mn >= (unsigned)tgt)) break;
        }
    }
    __syncthreads();
}

__global__ void zero_kernel(float* __restrict__ p, int n) {
    int i = blockIdx.x * 256 + threadIdx.x;
    if (i < n) p[i] = 0.0f;
}

// W (= [Wx;Wh], 1280 x 4096) -> per-block LDS image:
// [jb(256)][ku(40)][plane(2)][lane(64)][j(8)]  (80 KB per jb, contiguous)
__global__ void packWz_kernel(const float* __restrict__ Wx, const float* __restrict__ Wh,
                              unsigned short* __restrict__ Wzf) {
    int e = blockIdx.x * 256 + threadIdx.x;
    if (e >= 1280 * 4096) return;
    int k = e >> 12, col = e & 4095;
    float w = (k < NDIN) ? Wx[(size_t)k * NG + col] : Wh[(size_t)(k - NDIN) * NG + col];
    float back;
    unsigned short w0 = bf_hi(w, &back);
    unsigned short w1 = bf_hi(w - back, &back);
    int g = col >> 10, j = col & 1023;
    int jb = j >> 2, jc = j & 3, n = g * 4 + jc;
    int ku = k >> 5, kr = k & 31;
    int lane = (kr >> 3) * 16 + n, j8 = kr & 7;
    size_t off = ((size_t)jb * 40 + ku) * 1024 + lane * 8 + j8;
    Wzf[off] = w0;          // plane 0 (hi)
    Wzf[off + 512] = w1;    // plane 1 (lo)
}

// x ([64][512][256]) -> A-frag order [t][ku(8)][mb(4)][lane(64)][j(8)], hi/lo
__global__ void packX_kernel(const float* __restrict__ x,
                             unsigned short* __restrict__ xf0, unsigned short* __restrict__ xf1) {
    int e = blockIdx.x * 256 + threadIdx.x;
    if (e >= NB * NT * NDIN) return;
    int k = e & 255, t = (e >> 8) & 511, m = e >> 17;
    float v = x[e];
    float back;
    unsigned short a0 = bf_hi(v, &back);
    unsigned short a1 = bf_hi(v - back, &back);
    int ku = k >> 5, kr = k & 31, mb = m >> 4;
    int lane = (kr >> 3) * 16 + (m & 15), j = kr & 7;
    size_t off = ((((size_t)t * 8 + ku) * 4 + mb) * 64 + lane) * 8 + j;
    xf0[off] = a0; xf1[off] = a1;
}

// Wo (1024 x 256) -> B-frag order [nb(16)][ku(32)][lane(64)][j(8)], hi/lo
__global__ void packWo_kernel(const float* __restrict__ Wo,
                              unsigned short* __restrict__ Wo0f, unsigned short* __restrict__ Wo1f) {
    int e = blockIdx.x * 256 + threadIdx.x;
    if (e >= NH * NDOUT) return;
    int k = e >> 8, n = e & 255;
    float w = Wo[e];
    float back;
    unsigned short w0 = bf_hi(w, &back);
    unsigned short w1 = bf_hi(w - back, &back);
    int nb = n >> 4, nl = n & 15, ku = k >> 5, kr = k & 31;
    int lane = (kr >> 3) * 16 + nl, j = kr & 7;
    size_t off = (((size_t)nb * 32 + ku) * 64 + lane) * 8 + j;
    Wo0f[off] = w0; Wo1f[off] = w1;
}

// z h-load set (one ku = w*4+kk of the h slab): 8 x 16B loads
#define ZLOAD(S0, S1, kk) do {                                                    \
    const unsigned short* _p = hb0 + (size_t)(w4 + (kk)) * 2048 + lane8;          \
    S0[0] = *(const short8*)(_p);        S0[1] = *(const short8*)(_p + 512);      \
    S0[2] = *(const short8*)(_p + 1024); S0[3] = *(const short8*)(_p + 1536);     \
    const unsigned short* _q = _p + 65536;                                        \
    S1[0] = *(const short8*)(_q);        S1[1] = *(const short8*)(_q + 512);      \
    S1[2] = *(const short8*)(_q + 1024); S1[3] = *(const short8*)(_q + 1536);     \
} while (0)

// z MFMA set for one h-ku (3 planes x 4 mb)
#define ZMFMA(S0, S1, kk) do {                                                    \
    const unsigned short* _wp = wlds + (8 + w4 + (kk)) * 1024 + lane8;            \
    short8 _Wh = *(const short8*)(_wp);                                           \
    short8 _Wl = *(const short8*)(_wp + 512);                                     \
    acc[0] = __builtin_amdgcn_mfma_f32_16x16x32_bf16(S0[0], _Wh, acc[0], 0, 0, 0);\
    acc[0] = __builtin_amdgcn_mfma_f32_16x16x32_bf16(S0[0], _Wl, acc[0], 0, 0, 0);\
    acc[0] = __builtin_amdgcn_mfma_f32_16x16x32_bf16(S1[0], _Wh, acc[0], 0, 0, 0);\
    acc[1] = __builtin_amdgcn_mfma_f32_16x16x32_bf16(S0[1], _Wh, acc[1], 0, 0, 0);\
    acc[1] = __builtin_amdgcn_mfma_f32_16x16x32_bf16(S0[1], _Wl, acc[1], 0, 0, 0);\
    acc[1] = __builtin_amdgcn_mfma_f32_16x16x32_bf16(S1[1], _Wh, acc[1], 0, 0, 0);\
    acc[2] = __builtin_amdgcn_mfma_f32_16x16x32_bf16(S0[2], _Wh, acc[2], 0, 0, 0);\
    acc[2] = __builtin_amdgcn_mfma_f32_16x16x32_bf16(S0[2], _Wl, acc[2], 0, 0, 0);\
    acc[2] = __builtin_amdgcn_mfma_f32_16x16x32_bf16(S1[2], _Wh, acc[2], 0, 0, 0);\
    acc[3] = __builtin_amdgcn_mfma_f32_16x16x32_bf16(S0[3], _Wh, acc[3], 0, 0, 0);\
    acc[3] = __builtin_amdgcn_mfma_f32_16x16x32_bf16(S0[3], _Wl, acc[3], 0, 0, 0);\
    acc[3] = __builtin_amdgcn_mfma_f32_16x16x32_bf16(S1[3], _Wh, acc[3], 0, 0, 0);\
} while (0)

// x-partial for step tt: wave's x-ku = w, 4 mb x 3 MFMA, result REPLACES acc
#define XPART(tt) do {                                                            \
    const unsigned short* _xp0 = xf0 + ((size_t)(tt) * 8 + w) * 2048 + lane8;     \
    const unsigned short* _xp1 = xf1 + ((size_t)(tt) * 8 + w) * 2048 + lane8;     \
    short8 _X0[4], _X1[4];                                                        \
    _Pragma("unroll")                                                             \
    for (int _mb = 0; _mb < 4; ++_mb) {                                           \
        _X0[_mb] = *(const short8*)(_xp0 + _mb * 512);                            \
        _X1[_mb] = *(const short8*)(_xp1 + _mb * 512);                            \
    }                                                                             \
    const short8 _Wh = *(const short8*)(wlds + w * 1024 + lane8);                 \
    const short8 _Wl = *(const short8*)(wlds + w * 1024 + 512 + lane8);           \
    _Pragma("unroll")                                                             \
    for (int _mb = 0; _mb < 4; ++_mb) {                                           \
        float4v _a = (float4v){0.f, 0.f, 0.f, 0.f};                               \
        _a = __builtin_amdgcn_mfma_f32_16x16x32_bf16(_X0[_mb], _Wh, _a, 0, 0, 0); \
        _a = __builtin_amdgcn_mfma_f32_16x16x32_bf16(_X0[_mb], _Wl, _a, 0, 0, 0); \
        _a = __builtin_amdgcn_mfma_f32_16x16x32_bf16(_X1[_mb], _Wh, _a, 0, 0, 0); \
        acc[_mb] = _a;                                                            \
    }                                                                             \
} while (0)

// ================= 256-block persistent kernel (dataflow sync) =================
__global__ __launch_bounds__(512, 2) void persist_z256_kernel(
    const unsigned short* __restrict__ Wzf,
    const unsigned short* __restrict__ xf0, const unsigned short* __restrict__ xf1,
    const unsigned short* __restrict__ Wo0f, const unsigned short* __restrict__ Wo1f,
    unsigned short* __restrict__ hh, float* __restrict__ opart,
    const float* __restrict__ bias, const float* __restrict__ bo,
    float* __restrict__ out, unsigned* __restrict__ bar)
{
    extern __shared__ char dynlds[];
    unsigned short* wlds = (unsigned short*)dynlds;          // [40][2][64][8] = 80 KB
    float* red  = (float*)(dynlds + 81920);                  // [8][1024] z splitK slabs
    float* red2 = (float*)(dynlds + 114688);                 // [8][256] proj slabs

    const int bid = blockIdx.x, tid = threadIdx.x;
    const int lane = tid & 63, w = tid >> 6;
    const int lane8 = lane * 8, w4 = w * 4;

    // ---- one-time: W slice -> LDS (80 KB straight copy) ----
    {
        const unsigned short* src = Wzf + (size_t)bid * 40960;
        for (int i = tid; i < 5120; i += 512)
            *(short8*)(wlds + i * 8) = *(const short8*)(src + i * 8);
    }
    __syncthreads();

    // ---- per-thread gate-math constants (threads 0..255 own (row, col)) ----
    const int grow = tid >> 2, gjc = tid & 3;
    const int gj = bid * 4 + gjc;                            // global h-col
    const float b_i = bias[gj], b_f = bias[NH + gj], b_g = bias[2 * NH + gj], b_o = bias[3 * NH + gj];
    const int zb = ((grow >> 4) * 64 + (((grow & 15) >> 2) * 16) + gjc) * 4 + (grow & 3);
    // packed h-store address (4 cols of a row are 4 consecutive shorts)
    const int kuh = bid >> 3, krh3 = (bid & 7) >> 1, j80 = (bid & 1) * 4;
    const size_t hp = ((size_t)(kuh * 4 + (grow >> 4))) * 512
                    + (krh3 * 16 + (grow & 15)) * 8 + j80;
    float creg = 0.0f;                                       // cell state, register-resident

    // ---- proj constants: block owns tile (mbp,nbp) x K-quarter kq; wave owns 1 ku
    const int kq = bid & 3, tt0 = bid >> 2;
    const int mbp = tt0 >> 4, nbp = tt0 & 15;
    const int kup = kq * 8 + w;
    const size_t wo_off = (((size_t)nbp * 32 + kup) * 64 + lane) * 8;
    const short8 PWh = *(const short8*)(Wo0f + wo_off);      // Wo frags loop-invariant
    const short8 PWl = *(const short8*)(Wo1f + wo_off);

    float4v acc[4];
    XPART(0);                                                // prologue: x(0) partial

    for (int t = 0; t <= NT + 2; ++t) {
        const unsigned short* hb0 = hh + (size_t)t * HSTEP;  // h(t) slab, hi plane

        if (t >= NT) wait_full(bar, t);                      // tail only (3 iters)

        if (t < NT) {
            // ---- z h-part: per-ku producer poll folded into the load sequence.
            // Poll ku's 8-producer flag line (one 128B line), then load it;
            // later polls overlap earlier kus' in-flight loads.
            short8 A0[4][4], A1[4][4];
            KUPOLL(0, t); ZLOAD(A0[0], A1[0], 0);
            KUPOLL(1, t); ZLOAD(A0[1], A1[1], 1);
            KUPOLL(2, t); ZLOAD(A0[2], A1[2], 2);
            KUPOLL(3, t); ZLOAD(A0[3], A1[3], 3);
            ZMFMA(A0[0], A1[0], 0);
            ZMFMA(A0[1], A1[1], 1);
            ZMFMA(A0[2], A1[2], 2);
            ZMFMA(A0[3], A1[3], 3);

            // splitK slabs to LDS (consumes acc)
            float* slab = red + w * 1024;
            #pragma unroll
            for (int mb = 0; mb < 4; ++mb)
                *(float4v*)&slab[(mb * 64 + lane) * 4] = acc[mb];

            __syncthreads();

            if (tid < 256) {
                // fused splitK reduce + gate math + packed h(t+1) store
                float zi = b_i, zf = b_f, zg = b_g, zo = b_o;
                #pragma unroll
                for (int ww = 0; ww < 8; ++ww) {
                    const float* s = red + ww * 1024;
                    zi += s[zb]; zf += s[zb + 16]; zg += s[zb + 32]; zo += s[zb + 48];
                }
                float iv = sigf(zi), fv = sigf(zf), gv = tanhf(zg), ov = sigf(zo);
                creg = fv * creg + iv * gv;
                float hv = ov * tanhf(creg);
                float back;
                unsigned short h0 = bf_hi(hv, &back);
                unsigned short h1 = bf_hi(hv - back, &back);
                unsigned v = (unsigned)h0 | ((unsigned)h1 << 16);
                const int base = lane & ~3;                  // 4 cols = 4 consecutive lanes
                unsigned v0 = __shfl(v, base, 64);
                unsigned v1 = __shfl(v, base + 1, 64);
                unsigned v2 = __shfl(v, base + 2, 64);
                unsigned v3 = __shfl(v, base + 3, 64);
                if ((lane & 3) == 0) {
                    uint2v hi2, lo2;
                    hi2[0] = (v0 & 0xFFFFu) | (v1 << 16);
                    hi2[1] = (v2 & 0xFFFFu) | (v3 << 16);
                    lo2[0] = (v0 >> 16) | (v1 & 0xFFFF0000u);
                    lo2[1] = (v2 >> 16) | (v3 & 0xFFFF0000u);
                    unsigned short* hw = hh + (size_t)(t + 1) * HSTEP;
                    sc_store_dwordx2(hw + hp, hi2);
                    sc_store_dwordx2(hw + hp + 65536, lo2);  // lo plane
                }
            }
        }

        flag_arrive(bar, bid, t);

        // ======== post-flag work: consumed only at later epochs ====
        const int projA = (t >= 1 && t <= NT);
        short8 PAh, PAl;
        if (projA) {
            // proj A loads (h(t) fully confirmed by this block's z-phase polls)
            const unsigned short* ap = hb0 + (size_t)(kup * 4 + mbp) * 512 + lane8;
            PAh = *(const short8*)ap;
            PAl = *(const short8*)(ap + 65536);
        }

        if (t + 1 < NT) XPART(t + 1);                        // next-step x partial

        if (projA) {
            float4v pacc = (float4v){0.f, 0.f, 0.f, 0.f};
            pacc = __builtin_amdgcn_mfma_f32_16x16x32_bf16(PAh, PWh, pacc, 0, 0, 0);
            pacc = __builtin_amdgcn_mfma_f32_16x16x32_bf16(PAh, PWl, pacc, 0, 0, 0);
            pacc = __builtin_amdgcn_mfma_f32_16x16x32_bf16(PAl, PWh, pacc, 0, 0, 0);
            *(float4v*)&red2[(w * 64 + lane) * 4] = pacc;
            __syncthreads();
            if (tid < 256) {
                // proj reduce, coalesced store into 4-slab opart ring (slab t&3)
                const int c = tid & 15, rr = (tid >> 4) & 3, hb4 = tid >> 6;
                const int p = (hb4 * 16 + c) * 4 + rr;
                float s = 0.f;
                #pragma unroll
                for (int ww = 0; ww < 8; ++ww) s += red2[ww * 256 + p];
                const int prow = mbp * 16 + hb4 * 4 + rr;
                const int pcol = nbp * 16 + c;
                sc_store_dword(opart + (size_t)(t & 3) * 65536 + (size_t)kq * 16384
                               + (size_t)prow * NDOUT + pcol, s);
            }
        }

        if (bid < 8 && t >= 3) {
            // ---- outred: opart slab (t-2)&3 (proj of h step t-3) -> out row t-3 ----
            const float* op = opart + (size_t)((t - 2) & 3) * 65536;
            int idx = bid * 512 + tid;                       // [0,4096)
            int m = idx >> 6, oc4 = (idx & 63) * 4;
            float4v s0, s1, s2, s3;
            LD4(s0, s1, s2, s3,
                &op[(size_t)m * NDOUT + oc4],
                &op[16384 + (size_t)m * NDOUT + oc4],
                &op[32768 + (size_t)m * NDOUT + oc4],
                &op[49152 + (size_t)m * NDOUT + oc4]);
            float4v bv = *(const float4v*)&bo[oc4];
            float4v v = s0 + s1 + s2 + s3 + bv;
            float4v rr;
            rr[0] = fmaxf(v[0], 0.f); rr[1] = fmaxf(v[1], 0.f);
            rr[2] = fmaxf(v[2], 0.f); rr[3] = fmaxf(v[3], 0.f);
            *(float4v*)&out[((size_t)m * NT + (t - 3)) * NDOUT + oc4] = rr;
        }
    }
}

extern "C" void kernel_launch(void* const* d_in, const int* in_sizes, int n_in,
                              void* d_out, int out_size, void* d_ws, size_t ws_size,
                              hipStream_t stream) {
    const float* x  = (const float*)d_in[0];
    const float* Wx = (const float*)d_in[1];
    const float* Wh = (const float*)d_in[2];
    const float* b  = (const float*)d_in[3];
    const float* Wo = (const float*)d_in[4];
    const float* bo = (const float*)d_in[5];
    float* out = (float*)d_out;
    char* ws = (char*)d_ws;

    const size_t hh_bytes = (size_t)(NT + 3) * HSTEP * 2;    // 515 x 256 KB

    size_t off = 0;
    unsigned* bar = (unsigned*)(ws + off);             off += 4096;   // 256 flags @16B stride
    unsigned short* hh = (unsigned short*)(ws + off);  off += hh_bytes;
    size_t zero_floats = (4096 + (size_t)HSTEP * 2) / 4;      // bar + hh slab0
    float* opart = (float*)(ws + off);                 off += (size_t)4 * 4 * NB * NDOUT * 4;  // 1 MB ring
    unsigned short* Wzf = (unsigned short*)(ws + off); off += (size_t)1280 * 4096 * 2 * 2;     // 21 MB
    unsigned short* Wo0f = (unsigned short*)(ws + off); off += (size_t)NH * NDOUT * 2;
    unsigned short* Wo1f = (unsigned short*)(ws + off); off += (size_t)NH * NDOUT * 2;
    unsigned short* xf0 = (unsigned short*)(ws + off); off += (size_t)NB * NT * NDIN * 2;
    unsigned short* xf1 = (unsigned short*)(ws + off); off += (size_t)NB * NT * NDIN * 2;

    zero_kernel<<<(int)((zero_floats + 255) / 256), 256, 0, stream>>>((float*)ws, (int)zero_floats);
    packWz_kernel<<<(1280 * 4096 + 255) / 256, 256, 0, stream>>>(Wx, Wh, Wzf);
    packX_kernel<<<(NB * NT * NDIN + 255) / 256, 256, 0, stream>>>(x, xf0, xf1);
    packWo_kernel<<<(NH * NDOUT + 255) / 256, 256, 0, stream>>>(Wo, Wo0f, Wo1f);

    void* args[] = {(void*)&Wzf, (void*)&xf0, (void*)&xf1, (void*)&Wo0f, (void*)&Wo1f,
                    (void*)&hh, (void*)&opart, (void*)&b, (void*)&bo, (void*)&out, (void*)&bar};
    hipLaunchCooperativeKernel((void*)persist_z256_kernel, dim3(GRIDN), dim3(512),
                               args, (unsigned)LDSB, stream);
}

// Round 13
// 3098.063 us; speedup vs baseline: 2.3499x; 1.0154x over previous
//
#include <hip/hip_runtime.h>
#include <hip/hip_bf16.h>
#include <math.h>

#define NB 64
#define NT 512
#define NDIN 256
#define NH 1024
#define NG 4096
#define NDOUT 256

// 256 blocks: ALL do z (4 h-cols each, 8-wave splitK) AND proj (1 tile x K-quarter);
// blocks [0,8) also outred. Dataflow sync: each z-wave polls its 32 producer
// flags (merged, 4 cache lines) then issues all 32 h-loads via inline asm with
// counted vmcnt waits -- one LLC round for the whole load phase.
#define GRIDN 256
#define LDSB 122880        // 80K Wz + 32K red(z) + 8K red2(proj)
#define HSTEP 131072       // shorts per h time-slab: [v(2)][ku(32)][mb(4)][512]

typedef __attribute__((ext_vector_type(8))) short short8;
typedef __attribute__((ext_vector_type(4))) float float4v;
typedef __attribute__((ext_vector_type(2))) unsigned uint2v;

__device__ __forceinline__ float sigf(float v) { return 1.0f / (1.0f + expf(-v)); }

__device__ __forceinline__ unsigned short bf_hi(float v, float* back) {
    __hip_bfloat16 b = __float2bfloat16(v);
    *back = __bfloat162float(b);
    union { __hip_bfloat16 b; unsigned short u; } cv; cv.b = b;
    return cv.u;
}

// ---- device-coherent (LLC) helpers ----
#define LD4(o0,o1,o2,o3,p0,p1,p2,p3)                                             \
  asm volatile("global_load_dwordx4 %0, %4, off sc0 sc1\n\t"                     \
               "global_load_dwordx4 %1, %5, off sc0 sc1\n\t"                     \
               "global_load_dwordx4 %2, %6, off sc0 sc1\n\t"                     \
               "global_load_dwordx4 %3, %7, off sc0 sc1\n\t"                     \
               "s_waitcnt vmcnt(0)"                                              \
               : "=&v"(o0),"=&v"(o1),"=&v"(o2),"=&v"(o3)                         \
               : "v"(p0),"v"(p1),"v"(p2),"v"(p3) : "memory")

// cached (L2-shareable) async load, completion via counted vmcnt later
#define GLD(dst, p)                                                              \
  asm volatile("global_load_dwordx4 %0, %1, off" : "=&v"(dst) : "v"(p) : "memory")

__device__ __forceinline__ void sc_store_dword(float* p, float v) {
    asm volatile("global_store_dword %0, %1, off sc0 sc1" :: "v"(p), "v"(v) : "memory");
}
__device__ __forceinline__ void sc_store_dwordx2(unsigned short* p, uint2v v) {
    asm volatile("global_store_dwordx2 %0, %1, off sc0 sc1" :: "v"(p), "v"(v) : "memory");
}

// ---- flags: one per block, 16B stride. Flag value t+1 means: this block's
// h(t+1) stores AND all its stores from iterations <= t-1 (incl. proj(t-1))
// have drained to the LLC (vmcnt(0) precedes every flag store).
__device__ __forceinline__ void flag_arrive(unsigned* bar, int bid, int t) {
    asm volatile("s_waitcnt vmcnt(0)" ::: "memory");   // drain ALL own sc-stores
    __syncthreads();                                   // all waves' stores drained
    if (threadIdx.x == 0)
        __hip_atomic_store(bar + (unsigned)bid * 4, (unsigned)(t + 1),
                           __ATOMIC_RELAXED, __HIP_MEMORY_SCOPE_AGENT);
}

// full wait (tail iterations only): wave 0 polls all 256 flags >= tgt
__device__ __forceinline__ void wait_full(unsigned* bar, int tgt) {
    if (threadIdx.x < 64) {
        unsigned* f = bar + threadIdx.x * 4;
        for (;;) {
            unsigned v0 = __hip_atomic_load(f,       __ATOMIC_RELAXED, __HIP_MEMORY_SCOPE_AGENT);
            unsigned v1 = __hip_atomic_load(f + 256, __ATOMIC_RELAXED, __HIP_MEMORY_SCOPE_AGENT);
            unsigned v2 = __hip_atomic_load(f + 512, __ATOMIC_RELAXED, __HIP_MEMORY_SCOPE_AGENT);
            unsigned v3 = __hip_atomic_load(f + 768, __ATOMIC_RELAXED, __HIP_MEMORY_SCOPE_AGENT);
            unsigned mn = min(min(v0, v1), min(v2, v3));
            if (__all(mn >= (unsigned)tgt)) break;
        }
    }
    __syncthreads();
}

__global__ void zero_kernel(float* __restrict__ p, int n) {
    int i = blockIdx.x * 256 + threadIdx.x;
    if (i < n) p[i] = 0.0f;
}

// W (= [Wx;Wh], 1280 x 4096) -> per-block LDS image:
// [jb(256)][ku(40)][plane(2)][lane(64)][j(8)]  (80 KB per jb, contiguous)
__global__ void packWz_kernel(const float* __restrict__ Wx, const float* __restrict__ Wh,
                              unsigned short* __restrict__ Wzf) {
    int e = blockIdx.x * 256 + threadIdx.x;
    if (e >= 1280 * 4096) return;
    int k = e >> 12, col = e & 4095;
    float w = (k < NDIN) ? Wx[(size_t)k * NG + col] : Wh[(size_t)(k - NDIN) * NG + col];
    float back;
    unsigned short w0 = bf_hi(w, &back);
    unsigned short w1 = bf_hi(w - back, &back);
    int g = col >> 10, j = col & 1023;
    int jb = j >> 2, jc = j & 3, n = g * 4 + jc;
    int ku = k >> 5, kr = k & 31;
    int lane = (kr >> 3) * 16 + n, j8 = kr & 7;
    size_t off = ((size_t)jb * 40 + ku) * 1024 + lane * 8 + j8;
    Wzf[off] = w0;          // plane 0 (hi)
    Wzf[off + 512] = w1;    // plane 1 (lo)
}

// x ([64][512][256]) -> A-frag order [t][ku(8)][mb(4)][lane(64)][j(8)], hi/lo
__global__ void packX_kernel(const float* __restrict__ x,
                             unsigned short* __restrict__ xf0, unsigned short* __restrict__ xf1) {
    int e = blockIdx.x * 256 + threadIdx.x;
    if (e >= NB * NT * NDIN) return;
    int k = e & 255, t = (e >> 8) & 511, m = e >> 17;
    float v = x[e];
    float back;
    unsigned short a0 = bf_hi(v, &back);
    unsigned short a1 = bf_hi(v - back, &back);
    int ku = k >> 5, kr = k & 31, mb = m >> 4;
    int lane = (kr >> 3) * 16 + (m & 15), j = kr & 7;
    size_t off = ((((size_t)t * 8 + ku) * 4 + mb) * 64 + lane) * 8 + j;
    xf0[off] = a0; xf1[off] = a1;
}

// Wo (1024 x 256) -> B-frag order [nb(16)][ku(32)][lane(64)][j(8)], hi/lo
__global__ void packWo_kernel(const float* __restrict__ Wo,
                              unsigned short* __restrict__ Wo0f, unsigned short* __restrict__ Wo1f) {
    int e = blockIdx.x * 256 + threadIdx.x;
    if (e >= NH * NDOUT) return;
    int k = e >> 8, n = e & 255;
    float w = Wo[e];
    float back;
    unsigned short w0 = bf_hi(w, &back);
    unsigned short w1 = bf_hi(w - back, &back);
    int nb = n >> 4, nl = n & 15, ku = k >> 5, kr = k & 31;
    int lane = (kr >> 3) * 16 + nl, j = kr & 7;
    size_t off = (((size_t)nb * 32 + ku) * 64 + lane) * 8 + j;
    Wo0f[off] = w0; Wo1f[off] = w1;
}

// z MFMA set for one h-ku (3 planes x 4 mb)
#define ZMFMA(S0, S1, kk) do {                                                    \
    const unsigned short* _wp = wlds + (8 + w4 + (kk)) * 1024 + lane8;            \
    short8 _Wh = *(const short8*)(_wp);                                           \
    short8 _Wl = *(const short8*)(_wp + 512);                                     \
    acc[0] = __builtin_amdgcn_mfma_f32_16x16x32_bf16(S0[0], _Wh, acc[0], 0, 0, 0);\
    acc[0] = __builtin_amdgcn_mfma_f32_16x16x32_bf16(S0[0], _Wl, acc[0], 0, 0, 0);\
    acc[0] = __builtin_amdgcn_mfma_f32_16x16x32_bf16(S1[0], _Wh, acc[0], 0, 0, 0);\
    acc[1] = __builtin_amdgcn_mfma_f32_16x16x32_bf16(S0[1], _Wh, acc[1], 0, 0, 0);\
    acc[1] = __builtin_amdgcn_mfma_f32_16x16x32_bf16(S0[1], _Wl, acc[1], 0, 0, 0);\
    acc[1] = __builtin_amdgcn_mfma_f32_16x16x32_bf16(S1[1], _Wh, acc[1], 0, 0, 0);\
    acc[2] = __builtin_amdgcn_mfma_f32_16x16x32_bf16(S0[2], _Wh, acc[2], 0, 0, 0);\
    acc[2] = __builtin_amdgcn_mfma_f32_16x16x32_bf16(S0[2], _Wl, acc[2], 0, 0, 0);\
    acc[2] = __builtin_amdgcn_mfma_f32_16x16x32_bf16(S1[2], _Wh, acc[2], 0, 0, 0);\
    acc[3] = __builtin_amdgcn_mfma_f32_16x16x32_bf16(S0[3], _Wh, acc[3], 0, 0, 0);\
    acc[3] = __builtin_amdgcn_mfma_f32_16x16x32_bf16(S0[3], _Wl, acc[3], 0, 0, 0);\
    acc[3] = __builtin_amdgcn_mfma_f32_16x16x32_bf16(S1[3], _Wh, acc[3], 0, 0, 0);\
} while (0)

// x-partial for step tt: wave's x-ku = w, 4 mb x 3 MFMA, result REPLACES acc
#define XPART(tt) do {                                                            \
    const unsigned short* _xp0 = xf0 + ((size_t)(tt) * 8 + w) * 2048 + lane8;     \
    const unsigned short* _xp1 = xf1 + ((size_t)(tt) * 8 + w) * 2048 + lane8;     \
    short8 _X0[4], _X1[4];                                                        \
    _Pragma("unroll")                                                             \
    for (int _mb = 0; _mb < 4; ++_mb) {                                           \
        _X0[_mb] = *(const short8*)(_xp0 + _mb * 512);                            \
        _X1[_mb] = *(const short8*)(_xp1 + _mb * 512);                            \
    }                                                                             \
    const short8 _Wh = *(const short8*)(wlds + w * 1024 + lane8);                 \
    const short8 _Wl = *(const short8*)(wlds + w * 1024 + 512 + lane8);           \
    _Pragma("unroll")                                                             \
    for (int _mb = 0; _mb < 4; ++_mb) {                                           \
        float4v _a = (float4v){0.f, 0.f, 0.f, 0.f};                               \
        _a = __builtin_amdgcn_mfma_f32_16x16x32_bf16(_X0[_mb], _Wh, _a, 0, 0, 0); \
        _a = __builtin_amdgcn_mfma_f32_16x16x32_bf16(_X0[_mb], _Wl, _a, 0, 0, 0); \
        _a = __builtin_amdgcn_mfma_f32_16x16x32_bf16(_X1[_mb], _Wh, _a, 0, 0, 0); \
        acc[_mb] = _a;                                                            \
    }                                                                             \
} while (0)

// ================= 256-block persistent kernel (dataflow + asm load pipe) ======
__global__ __launch_bounds__(512, 2) void persist_z256_kernel(
    const unsigned short* __restrict__ Wzf,
    const unsigned short* __restrict__ xf0, const unsigned short* __restrict__ xf1,
    const unsigned short* __restrict__ Wo0f, const unsigned short* __restrict__ Wo1f,
    unsigned short* __restrict__ hh, float* __restrict__ opart,
    const float* __restrict__ bias, const float* __restrict__ bo,
    float* __restrict__ out, unsigned* __restrict__ bar)
{
    extern __shared__ char dynlds[];
    unsigned short* wlds = (unsigned short*)dynlds;          // [40][2][64][8] = 80 KB
    float* red  = (float*)(dynlds + 81920);                  // [8][1024] z splitK slabs
    float* red2 = (float*)(dynlds + 114688);                 // [8][256] proj slabs

    const int bid = blockIdx.x, tid = threadIdx.x;
    const int lane = tid & 63, w = tid >> 6;
    const int lane8 = lane * 8, w4 = w * 4;

    // ---- one-time: W slice -> LDS (80 KB straight copy) ----
    {
        const unsigned short* src = Wzf + (size_t)bid * 40960;
        for (int i = tid; i < 5120; i += 512)
            *(short8*)(wlds + i * 8) = *(const short8*)(src + i * 8);
    }
    __syncthreads();

    // ---- per-thread gate-math constants (threads 0..255 own (row, col)) ----
    const int grow = tid >> 2, gjc = tid & 3;
    const int gj = bid * 4 + gjc;                            // global h-col
    const float b_i = bias[gj], b_f = bias[NH + gj], b_g = bias[2 * NH + gj], b_o = bias[3 * NH + gj];
    const int zb = ((grow >> 4) * 64 + (((grow & 15) >> 2) * 16) + gjc) * 4 + (grow & 3);
    // packed h-store address (4 cols of a row are 4 consecutive shorts)
    const int kuh = bid >> 3, krh3 = (bid & 7) >> 1, j80 = (bid & 1) * 4;
    const size_t hp = ((size_t)(kuh * 4 + (grow >> 4))) * 512
                    + (krh3 * 16 + (grow & 15)) * 8 + j80;
    float creg = 0.0f;                                       // cell state, register-resident

    // ---- proj constants: block owns tile (mbp,nbp) x K-quarter kq; wave owns 1 ku
    const int kq = bid & 3, tt0 = bid >> 2;
    const int mbp = tt0 >> 4, nbp = tt0 & 15;
    const int kup = kq * 8 + w;
    const size_t wo_off = (((size_t)nbp * 32 + kup) * 64 + lane) * 8;
    const short8 PWh = *(const short8*)(Wo0f + wo_off);      // Wo frags loop-invariant
    const short8 PWl = *(const short8*)(Wo1f + wo_off);

    float4v acc[4];
    XPART(0);                                                // prologue: x(0) partial

    for (int t = 0; t <= NT + 2; ++t) {
        const unsigned short* hb0 = hh + (size_t)t * HSTEP;  // h(t) slab, hi plane

        if (t >= NT) wait_full(bar, t);                      // tail only (3 iters)

        if (t < NT) {
            // ---- merged producer poll: this wave's 4 h-kus have 32 producers
            // (blocks 32w..32w+31); lanes 0..31 watch one flag each.
            {
                unsigned* _f = bar + ((unsigned)(w4 * 8) + (lane & 31)) * 4;
                for (;;) {
                    unsigned _v = __hip_atomic_load(_f, __ATOMIC_RELAXED,
                                                    __HIP_MEMORY_SCOPE_AGENT);
                    if (__all(_v >= (unsigned)t)) break;
                }
                asm volatile("" ::: "memory");
            }

            // ---- issue ALL 32 h-loads back-to-back (asm, cached), then
            // counted vmcnt waits: one LLC round covers the whole phase.
            short8 A0[4][4], A1[4][4];
            #pragma unroll
            for (int kk = 0; kk < 4; ++kk) {
                const unsigned short* _p = hb0 + (size_t)(w4 + kk) * 2048 + lane8;
                GLD(A0[kk][0], _p);        GLD(A0[kk][1], _p + 512);
                GLD(A0[kk][2], _p + 1024); GLD(A0[kk][3], _p + 1536);
                const unsigned short* _q = _p + 65536;
                GLD(A1[kk][0], _q);        GLD(A1[kk][1], _q + 512);
                GLD(A1[kk][2], _q + 1024); GLD(A1[kk][3], _q + 1536);
            }
            asm volatile("s_waitcnt vmcnt(24)" ::: "memory");
            __builtin_amdgcn_sched_barrier(0);
            ZMFMA(A0[0], A1[0], 0);
            asm volatile("s_waitcnt vmcnt(16)" ::: "memory");
            __builtin_amdgcn_sched_barrier(0);
            ZMFMA(A0[1], A1[1], 1);
            asm volatile("s_waitcnt vmcnt(8)" ::: "memory");
            __builtin_amdgcn_sched_barrier(0);
            ZMFMA(A0[2], A1[2], 2);
            asm volatile("s_waitcnt vmcnt(0)" ::: "memory");
            __builtin_amdgcn_sched_barrier(0);
            ZMFMA(A0[3], A1[3], 3);

            // splitK slabs to LDS (consumes acc)
            float* slab = red + w * 1024;
            #pragma unroll
            for (int mb = 0; mb < 4; ++mb)
                *(float4v*)&slab[(mb * 64 + lane) * 4] = acc[mb];

            __syncthreads();

            if (tid < 256) {
                // fused splitK reduce + gate math + packed h(t+1) store
                float zi = b_i, zf = b_f, zg = b_g, zo = b_o;
                #pragma unroll
                for (int ww = 0; ww < 8; ++ww) {
                    const float* s = red + ww * 1024;
                    zi += s[zb]; zf += s[zb + 16]; zg += s[zb + 32]; zo += s[zb + 48];
                }
                float iv = sigf(zi), fv = sigf(zf), gv = tanhf(zg), ov = sigf(zo);
                creg = fv * creg + iv * gv;
                float hv = ov * tanhf(creg);
                float back;
                unsigned short h0 = bf_hi(hv, &back);
                unsigned short h1 = bf_hi(hv - back, &back);
                unsigned v = (unsigned)h0 | ((unsigned)h1 << 16);
                const int base = lane & ~3;                  // 4 cols = 4 consecutive lanes
                unsigned v0 = __shfl(v, base, 64);
                unsigned v1 = __shfl(v, base + 1, 64);
                unsigned v2 = __shfl(v, base + 2, 64);
                unsigned v3 = __shfl(v, base + 3, 64);
                if ((lane & 3) == 0) {
                    uint2v hi2, lo2;
                    hi2[0] = (v0 & 0xFFFFu) | (v1 << 16);
                    hi2[1] = (v2 & 0xFFFFu) | (v3 << 16);
                    lo2[0] = (v0 >> 16) | (v1 & 0xFFFF0000u);
                    lo2[1] = (v2 >> 16) | (v3 & 0xFFFF0000u);
                    unsigned short* hw = hh + (size_t)(t + 1) * HSTEP;
                    sc_store_dwordx2(hw + hp, hi2);
                    sc_store_dwordx2(hw + hp + 65536, lo2);  // lo plane
                }
            }
        }

        flag_arrive(bar, bid, t);

        // ======== post-flag work: consumed only at later epochs ====
        const int projA = (t >= 1 && t <= NT);
        short8 PAh, PAl;
        if (projA) {
            // proj A loads (h(t) fully confirmed by this block's z-phase polls)
            const unsigned short* ap = hb0 + (size_t)(kup * 4 + mbp) * 512 + lane8;
            PAh = *(const short8*)ap;
            PAl = *(const short8*)(ap + 65536);
        }

        if (t + 1 < NT) XPART(t + 1);                        // next-step x partial

        if (projA) {
            float4v pacc = (float4v){0.f, 0.f, 0.f, 0.f};
            pacc = __builtin_amdgcn_mfma_f32_16x16x32_bf16(PAh, PWh, pacc, 0, 0, 0);
            pacc = __builtin_amdgcn_mfma_f32_16x16x32_bf16(PAh, PWl, pacc, 0, 0, 0);
            pacc = __builtin_amdgcn_mfma_f32_16x16x32_bf16(PAl, PWh, pacc, 0, 0, 0);
            *(float4v*)&red2[(w * 64 + lane) * 4] = pacc;
            __syncthreads();
            if (tid < 256) {
                // proj reduce, coalesced store into 4-slab opart ring (slab t&3)
                const int c = tid & 15, rr = (tid >> 4) & 3, hb4 = tid >> 6;
                const int p = (hb4 * 16 + c) * 4 + rr;
                float s = 0.f;
                #pragma unroll
                for (int ww = 0; ww < 8; ++ww) s += red2[ww * 256 + p];
                const int prow = mbp * 16 + hb4 * 4 + rr;
                const int pcol = nbp * 16 + c;
                sc_store_dword(opart + (size_t)(t & 3) * 65536 + (size_t)kq * 16384
                               + (size_t)prow * NDOUT + pcol, s);
            }
        }

        if (bid < 8 && t >= 3) {
            // ---- outred: opart slab (t-2)&3 (proj of h step t-3) -> out row t-3 ----
            const float* op = opart + (size_t)((t - 2) & 3) * 65536;
            int idx = bid * 512 + tid;                       // [0,4096)
            int m = idx >> 6, oc4 = (idx & 63) * 4;
            float4v s0, s1, s2, s3;
            LD4(s0, s1, s2, s3,
                &op[(size_t)m * NDOUT + oc4],
                &op[16384 + (size_t)m * NDOUT + oc4],
                &op[32768 + (size_t)m * NDOUT + oc4],
                &op[49152 + (size_t)m * NDOUT + oc4]);
            float4v bv = *(const float4v*)&bo[oc4];
            float4v v = s0 + s1 + s2 + s3 + bv;
            float4v rr;
            rr[0] = fmaxf(v[0], 0.f); rr[1] = fmaxf(v[1], 0.f);
            rr[2] = fmaxf(v[2], 0.f); rr[3] = fmaxf(v[3], 0.f);
            *(float4v*)&out[((size_t)m * NT + (t - 3)) * NDOUT + oc4] = rr;
        }
    }
}

extern "C" void kernel_launch(void* const* d_in, const int* in_sizes, int n_in,
                              void* d_out, int out_size, void* d_ws, size_t ws_size,
                              hipStream_t stream) {
    const float* x  = (const float*)d_in[0];
    const float* Wx = (const float*)d_in[1];
    const float* Wh = (const float*)d_in[2];
    const float* b  = (const float*)d_in[3];
    const float* Wo = (const float*)d_in[4];
    const float* bo = (const float*)d_in[5];
    float* out = (float*)d_out;
    char* ws = (char*)d_ws;

    const size_t hh_bytes = (size_t)(NT + 3) * HSTEP * 2;    // 515 x 256 KB

    size_t off = 0;
    unsigned* bar = (unsigned*)(ws + off);             off += 4096;   // 256 flags @16B stride
    unsigned short* hh = (unsigned short*)(ws + off);  off += hh_bytes;
    size_t zero_floats = (4096 + (size_t)HSTEP * 2) / 4;      // bar + hh slab0
    float* opart = (float*)(ws + off);                 off += (size_t)4 * 4 * NB * NDOUT * 4;  // 1 MB ring
    unsigned short* Wzf = (unsigned short*)(ws + off); off += (size_t)1280 * 4096 * 2 * 2;     // 21 MB
    unsigned short* Wo0f = (unsigned short*)(ws + off); off += (size_t)NH * NDOUT * 2;
    unsigned short* Wo1f = (unsigned short*)(ws + off); off += (size_t)NH * NDOUT * 2;
    unsigned short* xf0 = (unsigned short*)(ws + off); off += (size_t)NB * NT * NDIN * 2;
    unsigned short* xf1 = (unsigned short*)(ws + off); off += (size_t)NB * NT * NDIN * 2;

    zero_kernel<<<(int)((zero_floats + 255) / 256), 256, 0, stream>>>((float*)ws, (int)zero_floats);
    packWz_kernel<<<(1280 * 4096 + 255) / 256, 256, 0, stream>>>(Wx, Wh, Wzf);
    packX_kernel<<<(NB * NT * NDIN + 255) / 256, 256, 0, stream>>>(x, xf0, xf1);
    packWo_kernel<<<(NH * NDOUT + 255) / 256, 256, 0, stream>>>(Wo, Wo0f, Wo1f);

    void* args[] = {(void*)&Wzf, (void*)&xf0, (void*)&xf1, (void*)&Wo0f, (void*)&Wo1f,
                    (void*)&hh, (void*)&opart, (void*)&b, (void*)&bo, (void*)&out, (void*)&bar};
    hipLaunchCooperativeKernel((void*)persist_z256_kernel, dim3(GRIDN), dim3(512),
                               args, (unsigned)LDSB, stream);
}